// Round 1
// baseline (818.754 us; speedup 1.0000x reference)
//
#include <hip/hip_runtime.h>
#include <cmath>

#define DEV __device__ __forceinline__

DEV float lrelu(float v) { return v > 0.f ? v : 0.2f * v; }

// ---------------- CSR build ----------------
__global__ void k_count(const int* __restrict__ ei, int* __restrict__ counts,
                        int E0, int ET) {
  int e = blockIdx.x * 256 + threadIdx.x;
  if (e >= ET) return;
  int dst = (e < E0) ? ei[E0 + e] : (e - E0);
  atomicAdd(&counts[dst], 1);
}

__global__ void k_scan(const int* __restrict__ counts, int* __restrict__ offs, int n) {
  __shared__ int sh[1024];
  __shared__ int carry;
  int t = threadIdx.x;
  if (t == 0) carry = 0;
  __syncthreads();
  for (int base = 0; base < n; base += 1024) {
    int v = (base + t < n) ? counts[base + t] : 0;
    sh[t] = v;
    __syncthreads();
    for (int o = 1; o < 1024; o <<= 1) {
      int tmp = (t >= o) ? sh[t - o] : 0;
      __syncthreads();
      sh[t] += tmp;
      __syncthreads();
    }
    if (base + t < n) offs[base + t] = carry + sh[t] - v;  // exclusive
    __syncthreads();
    if (t == 0) carry += sh[1023];
    __syncthreads();
  }
  if (t == 0) offs[n] = carry;
}

__global__ void k_scatter(const int* __restrict__ ei, const int* __restrict__ offs,
                          int* __restrict__ cursor, int* __restrict__ src_s,
                          int* __restrict__ dst_s, int E0, int ET) {
  int e = blockIdx.x * 256 + threadIdx.x;
  if (e >= ET) return;
  int src, dst;
  if (e < E0) { src = ei[e]; dst = ei[E0 + e]; }
  else        { src = e - E0; dst = e - E0; }
  int pos = offs[dst] + atomicAdd(&cursor[dst], 1);
  src_s[pos] = src;
  dst_s[pos] = dst;
}

// ---------------- LayerNorm (+opt act). ACT: 0 none, 1 relu, 2 elu ----------------
template<int C, int ACT>
__global__ void k_ln(const float* in, float* out, const float* g, const float* b) {
  constexpr int T = (C < 256) ? C : 256;
  constexpr int EPT = C / T;
  constexpr int NW = T / 64;
  int row = blockIdx.x, t = threadIdx.x;
  const float* ip = in + (size_t)row * C;
  float v[EPT];
  float s = 0.f, s2 = 0.f;
#pragma unroll
  for (int e = 0; e < EPT; ++e) { float xv = ip[t + e * T]; v[e] = xv; s += xv; s2 += xv * xv; }
#pragma unroll
  for (int m = 1; m <= 32; m <<= 1) { s += __shfl_xor(s, m); s2 += __shfl_xor(s2, m); }
  __shared__ float w1s[NW], w2s[NW];
  if (NW > 1) {
    if ((t & 63) == 0) { w1s[t >> 6] = s; w2s[t >> 6] = s2; }
    __syncthreads();
    s = 0.f; s2 = 0.f;
#pragma unroll
    for (int i = 0; i < NW; ++i) { s += w1s[i]; s2 += w2s[i]; }
  }
  float mu = s * (1.0f / C);
  float var = s2 * (1.0f / C) - mu * mu;
  float rs = rsqrtf(var + 1e-5f);
  float* op = out + (size_t)row * C;
#pragma unroll
  for (int e = 0; e < EPT; ++e) {
    int c = t + e * T;
    float y = (v[e] - mu) * rs * g[c] + b[c];
    if (ACT == 1) y = fmaxf(y, 0.f);
    if (ACT == 2) y = (y > 0.f) ? y : expm1f(y);
    op[c] = y;
  }
}

// ---------------- Dense: C = act(A[M,K] @ W[K,N] + bias) ----------------
template<int K, int N, int RPB, int ACT>
__global__ __launch_bounds__(256) void k_dense(const float* __restrict__ A,
                                               const float* __restrict__ W,
                                               const float* __restrict__ bias,
                                               float* __restrict__ Cc) {
  constexpr int NTC = (N < 256) ? N : 256;
  constexpr int NTR = 256 / NTC;
  constexpr int CPT = N / NTC;
  constexpr int RPT = RPB / NTR;
  __shared__ float As[RPB * K];
  int row0 = blockIdx.x * RPB;
  {
    const float4* Ag = reinterpret_cast<const float4*>(A + (size_t)row0 * K);
    float4* As4 = reinterpret_cast<float4*>(As);
    for (int i = threadIdx.x; i < RPB * K / 4; i += 256) As4[i] = Ag[i];
  }
  __syncthreads();
  int tc = threadIdx.x % NTC;
  int tr = threadIdx.x / NTC;
  float acc[RPT][CPT];
#pragma unroll
  for (int r = 0; r < RPT; ++r)
#pragma unroll
    for (int j = 0; j < CPT; ++j) acc[r][j] = 0.f;
  for (int k = 0; k < K; k += 4) {
    float w0[CPT], w1[CPT], w2[CPT], w3[CPT];
#pragma unroll
    for (int j = 0; j < CPT; ++j) {
      int c = tc + j * NTC;
      w0[j] = W[(k + 0) * N + c];
      w1[j] = W[(k + 1) * N + c];
      w2[j] = W[(k + 2) * N + c];
      w3[j] = W[(k + 3) * N + c];
    }
#pragma unroll
    for (int r = 0; r < RPT; ++r) {
      float4 av = *reinterpret_cast<const float4*>(&As[(tr + r * NTR) * K + k]);
#pragma unroll
      for (int j = 0; j < CPT; ++j) {
        acc[r][j] = fmaf(av.x, w0[j], acc[r][j]);
        acc[r][j] = fmaf(av.y, w1[j], acc[r][j]);
        acc[r][j] = fmaf(av.z, w2[j], acc[r][j]);
        acc[r][j] = fmaf(av.w, w3[j], acc[r][j]);
      }
    }
  }
#pragma unroll
  for (int r = 0; r < RPT; ++r) {
    int row = row0 + tr + r * NTR;
#pragma unroll
    for (int j = 0; j < CPT; ++j) {
      int c = tc + j * NTC;
      float v = acc[r][j] + bias[c];
      if (ACT == 1) v = fmaxf(v, 0.f);
      Cc[(size_t)row * N + c] = v;
    }
  }
}

// ---------------- GATv2 edge logits, layer 1 (4 heads x 128) ----------------
__global__ __launch_bounds__(256) void k_logits1(const int* __restrict__ src_s,
                                                 const int* __restrict__ dst_s,
                                                 const float* __restrict__ xl,
                                                 const float* __restrict__ xr,
                                                 const float* __restrict__ att,
                                                 float* __restrict__ logit, int ET) {
  int wid = threadIdx.x >> 6, lane = threadIdx.x & 63;
  int p = blockIdx.x * 4 + wid;
  if (p >= ET) return;
  int sn = src_s[p], dn = dst_s[p];
  const float4* xlp = reinterpret_cast<const float4*>(xl + (size_t)sn * 512);
  const float4* xrp = reinterpret_cast<const float4*>(xr + (size_t)dn * 512);
  const float4* at4 = reinterpret_cast<const float4*>(att);
  float pq[2];
#pragma unroll
  for (int q = 0; q < 2; ++q) {
    int f = lane + 64 * q;
    float4 a = xlp[f], c = xrp[f], w = at4[f];
    float v0 = lrelu(a.x + c.x);
    float v1 = lrelu(a.y + c.y);
    float v2 = lrelu(a.z + c.z);
    float v3 = lrelu(a.w + c.w);
    pq[q] = w.x * v0 + w.y * v1 + w.z * v2 + w.w * v3;
  }
#pragma unroll
  for (int m = 1; m <= 16; m <<= 1) {
    pq[0] += __shfl_xor(pq[0], m);
    pq[1] += __shfl_xor(pq[1], m);
  }
  if ((lane & 31) == 0) {
    int hb = lane >> 5;  // 0 for lanes 0-31 (heads 0/2), 1 for lanes 32-63 (heads 1/3)
    logit[(size_t)p * 4 + hb]     = pq[0];
    logit[(size_t)p * 4 + hb + 2] = pq[1];
  }
}

// ---------------- GATv2 edge logits, layer 2 (1 head x 128) ----------------
__global__ __launch_bounds__(256) void k_logits2(const int* __restrict__ src_s,
                                                 const int* __restrict__ dst_s,
                                                 const float* __restrict__ xl,
                                                 const float* __restrict__ xr,
                                                 const float* __restrict__ att,
                                                 float* __restrict__ logit, int ET) {
  int wid = threadIdx.x >> 6, lane = threadIdx.x & 63;
  int p = blockIdx.x * 4 + wid;
  if (p >= ET) return;
  int sn = src_s[p], dn = dst_s[p];
  const float2* a2 = reinterpret_cast<const float2*>(xl + (size_t)sn * 128);
  const float2* c2 = reinterpret_cast<const float2*>(xr + (size_t)dn * 128);
  const float2* w2 = reinterpret_cast<const float2*>(att);
  float2 a = a2[lane], c = c2[lane], w = w2[lane];
  float s = w.x * lrelu(a.x + c.x) + w.y * lrelu(a.y + c.y);
#pragma unroll
  for (int m = 1; m <= 32; m <<= 1) s += __shfl_xor(s, m);
  if (lane == 0) logit[p] = s;
}

// ---------------- GAT1 aggregate: block per dst node, 512 channels ----------------
__global__ __launch_bounds__(256) void k_agg1(const int* __restrict__ offs,
                                              const int* __restrict__ src_s,
                                              const float* __restrict__ logit,
                                              const float* __restrict__ xl,
                                              const float* __restrict__ bg,
                                              float* __restrict__ outg) {
  int n = blockIdx.x;
  int st = offs[n], en = offs[n + 1];
  int t = threadIdx.x;
  __shared__ float sm[4], sinv[4];
  __shared__ float wl[256];
  __shared__ int srcl[64];
  {  // per-head max & sum(exp), one wave per head
    int h = t >> 6, l = t & 63;
    float mx = -3.0e38f;
    for (int i = l; i < en - st; i += 64) mx = fmaxf(mx, logit[(size_t)(st + i) * 4 + h]);
#pragma unroll
    for (int m = 1; m <= 32; m <<= 1) mx = fmaxf(mx, __shfl_xor(mx, m));
    float se = 0.f;
    for (int i = l; i < en - st; i += 64) se += expf(logit[(size_t)(st + i) * 4 + h] - mx);
#pragma unroll
    for (int m = 1; m <= 32; m <<= 1) se += __shfl_xor(se, m);
    if (l == 0) { sm[h] = mx; sinv[h] = 1.0f / (se + 1e-16f); }
  }
  __syncthreads();
  float acc0 = 0.f, acc1 = 0.f;
  int h0 = t >> 7;  // head of channel t (0/1); channel t+256 is head h0+2
  for (int base = st; base < en; base += 64) {
    int len = min(64, en - base);
    if (t < len * 4) {
      int i = t >> 2, h = t & 3;
      wl[t] = expf(logit[(size_t)(base + i) * 4 + h] - sm[h]) * sinv[h];
    }
    if (t < len) srcl[t] = src_s[base + t];
    __syncthreads();
    for (int i = 0; i < len; ++i) {
      const float* xp = xl + (size_t)srcl[i] * 512;
      acc0 += wl[i * 4 + h0]     * xp[t];
      acc1 += wl[i * 4 + h0 + 2] * xp[t + 256];
    }
    __syncthreads();
  }
  float* op = outg + (size_t)n * 512;
  op[t]       = acc0 + bg[t];
  op[t + 256] = acc1 + bg[t + 256];
}

// ---------------- GAT2 aggregate: block per dst node, 128 channels ----------------
__global__ __launch_bounds__(128) void k_agg2(const int* __restrict__ offs,
                                              const int* __restrict__ src_s,
                                              const float* __restrict__ logit,
                                              const float* __restrict__ xl,
                                              const float* __restrict__ bg,
                                              float* __restrict__ outg) {
  int n = blockIdx.x;
  int st = offs[n], en = offs[n + 1];
  int t = threadIdx.x;
  __shared__ float sm1, sinv1;
  __shared__ float wl[64];
  __shared__ int srcl[64];
  if (t < 64) {
    float mx = -3.0e38f;
    for (int i = t; i < en - st; i += 64) mx = fmaxf(mx, logit[st + i]);
#pragma unroll
    for (int m = 1; m <= 32; m <<= 1) mx = fmaxf(mx, __shfl_xor(mx, m));
    float se = 0.f;
    for (int i = t; i < en - st; i += 64) se += expf(logit[st + i] - mx);
#pragma unroll
    for (int m = 1; m <= 32; m <<= 1) se += __shfl_xor(se, m);
    if (t == 0) { sm1 = mx; sinv1 = 1.0f / (se + 1e-16f); }
  }
  __syncthreads();
  float acc = 0.f;
  for (int base = st; base < en; base += 64) {
    int len = min(64, en - base);
    if (t < len) { wl[t] = expf(logit[base + t] - sm1) * sinv1; srcl[t] = src_s[base + t]; }
    __syncthreads();
    for (int i = 0; i < len; ++i) acc += wl[i] * xl[(size_t)srcl[i] * 128 + t];
    __syncthreads();
  }
  outg[(size_t)n * 128 + t] = acc + bg[t];
}

// ---------------- Fused MLP heads (wave per row) ----------------
__global__ __launch_bounds__(256) void k_head_ret(const float* __restrict__ in,
    const float* __restrict__ W1, const float* __restrict__ b1,
    const float* __restrict__ W2, const float* __restrict__ b2,
    const float* __restrict__ W3, const float* __restrict__ b3,
    float* __restrict__ out) {
  __shared__ float sh[4][224];
  int wid = threadIdx.x >> 6, lane = threadIdx.x & 63;
  int row = blockIdx.x * 4 + wid;
  const float2* rp = reinterpret_cast<const float2*>(in + (size_t)row * 128);
  float2 f2 = rp[lane];
  sh[wid][2 * lane] = f2.x;
  sh[wid][2 * lane + 1] = f2.y;
  __syncthreads();
  float a = b1[lane];
#pragma unroll 8
  for (int k = 0; k < 128; ++k) a = fmaf(sh[wid][k], W1[k * 64 + lane], a);
  sh[wid][128 + lane] = fmaxf(a, 0.f);
  __syncthreads();
  if (lane < 32) {
    float a2 = b2[lane];
#pragma unroll 8
    for (int k = 0; k < 64; ++k) a2 = fmaf(sh[wid][128 + k], W2[k * 32 + lane], a2);
    sh[wid][192 + lane] = fmaxf(a2, 0.f);
  }
  __syncthreads();
  if (lane == 0) {
    float a3 = b3[0];
#pragma unroll
    for (int k = 0; k < 32; ++k) a3 = fmaf(sh[wid][192 + k], W3[k], a3);
    out[row] = tanhf(a3) * 0.1f;
  }
}

__global__ __launch_bounds__(256) void k_head_mov(const float* __restrict__ in,
    const float* __restrict__ W1, const float* __restrict__ b1,
    const float* __restrict__ W2, const float* __restrict__ b2,
    float* __restrict__ out) {
  __shared__ float sh[4][192];
  int wid = threadIdx.x >> 6, lane = threadIdx.x & 63;
  int row = blockIdx.x * 4 + wid;
  const float2* rp = reinterpret_cast<const float2*>(in + (size_t)row * 128);
  float2 f2 = rp[lane];
  sh[wid][2 * lane] = f2.x;
  sh[wid][2 * lane + 1] = f2.y;
  __syncthreads();
  float a = b1[lane];
#pragma unroll 8
  for (int k = 0; k < 128; ++k) a = fmaf(sh[wid][k], W1[k * 64 + lane], a);
  sh[wid][128 + lane] = fmaxf(a, 0.f);
  __syncthreads();
  if (lane < 2) {
    float a2 = b2[lane];
#pragma unroll 8
    for (int k = 0; k < 64; ++k) a2 = fmaf(sh[wid][128 + k], W2[k * 2 + lane], a2);
    out[(size_t)row * 2 + lane] = a2;
  }
}

__global__ __launch_bounds__(256) void k_head_rank(const float* __restrict__ in,
    const float* __restrict__ W1, const float* __restrict__ b1,
    const float* __restrict__ W2, const float* __restrict__ b2,
    float* __restrict__ out) {
  __shared__ float sh[4][192];
  int wid = threadIdx.x >> 6, lane = threadIdx.x & 63;
  int row = blockIdx.x * 4 + wid;
  const float2* rp = reinterpret_cast<const float2*>(in + (size_t)row * 128);
  float2 f2 = rp[lane];
  sh[wid][2 * lane] = f2.x;
  sh[wid][2 * lane + 1] = f2.y;
  __syncthreads();
  float a = b1[lane];
#pragma unroll 8
  for (int k = 0; k < 128; ++k) a = fmaf(sh[wid][k], W1[k * 64 + lane], a);
  sh[wid][128 + lane] = fmaxf(a, 0.f);
  __syncthreads();
  if (lane == 0) {
    float a2 = b2[0];
#pragma unroll 8
    for (int k = 0; k < 64; ++k) a2 = fmaf(sh[wid][128 + k], W2[k], a2);
    out[row] = 1.0f / (1.0f + expf(-a2));
  }
}

// ---------------- launch ----------------
extern "C" void kernel_launch(void* const* d_in, const int* in_sizes, int n_in,
                              void* d_out, int out_size, void* d_ws, size_t ws_size,
                              hipStream_t stream) {
  const float* x     = (const float*)d_in[0];
  const int*   ei    = (const int*)  d_in[1];
  const float* fn_g  = (const float*)d_in[2];
  const float* fn_b  = (const float*)d_in[3];
  const float* W_in  = (const float*)d_in[4];
  const float* b_in  = (const float*)d_in[5];
  const float* Wl1   = (const float*)d_in[6];
  const float* bl1   = (const float*)d_in[7];
  const float* Wr1   = (const float*)d_in[8];
  const float* br1   = (const float*)d_in[9];
  const float* att1  = (const float*)d_in[10];
  const float* bg1   = (const float*)d_in[11];
  const float* Wl2   = (const float*)d_in[12];
  const float* bl2   = (const float*)d_in[13];
  const float* Wr2   = (const float*)d_in[14];
  const float* br2   = (const float*)d_in[15];
  const float* att2  = (const float*)d_in[16];
  const float* bg2   = (const float*)d_in[17];
  const float* ln1_g = (const float*)d_in[18];
  const float* ln1_b = (const float*)d_in[19];
  const float* ln2_g = (const float*)d_in[20];
  const float* ln2_b = (const float*)d_in[21];
  const float* Wrf   = (const float*)d_in[22];
  const float* brf   = (const float*)d_in[23];
  const float* rf_g  = (const float*)d_in[24];
  const float* rf_b  = (const float*)d_in[25];
  const float* Wcf   = (const float*)d_in[26];
  const float* bcf   = (const float*)d_in[27];
  const float* cf_g  = (const float*)d_in[28];
  const float* cf_b  = (const float*)d_in[29];
  const float* Wkf   = (const float*)d_in[30];
  const float* bkf   = (const float*)d_in[31];
  const float* kf_g  = (const float*)d_in[32];
  const float* kf_b  = (const float*)d_in[33];
  const float* Wr1h  = (const float*)d_in[34];
  const float* br1h  = (const float*)d_in[35];
  const float* Wr2h  = (const float*)d_in[36];
  const float* br2h  = (const float*)d_in[37];
  const float* Wr3h  = (const float*)d_in[38];
  const float* br3h  = (const float*)d_in[39];
  const float* Wc1h  = (const float*)d_in[40];
  const float* bc1h  = (const float*)d_in[41];
  const float* Wc2h  = (const float*)d_in[42];
  const float* bc2h  = (const float*)d_in[43];
  const float* Wk1h  = (const float*)d_in[44];
  const float* bk1h  = (const float*)d_in[45];
  const float* Wk2h  = (const float*)d_in[46];
  const float* bk2h  = (const float*)d_in[47];

  const int M  = in_sizes[0] / 128;   // 20000
  const int E0 = in_sizes[1] / 2;     // 320000
  const int ET = E0 + M;              // 340000

  char* base = (char*)d_ws;
  size_t off = 0;
  auto carve = [&](size_t bytes) -> char* {
    off = (off + 255) & ~(size_t)255;
    char* p = base + off;
    off += bytes;
    return p;
  };
  const size_t SZ512 = (size_t)M * 512 * sizeof(float);
  const size_t SZ128 = (size_t)M * 128 * sizeof(float);
  float* xl1 = (float*)carve(SZ512);
  float* xr1 = (float*)carve(SZ512);
  float* g1  = (float*)carve(SZ512);                       // g1 -> h1 in place
  float* hn  = (float*)carve(SZ128);                       // later xl2
  float* h0  = (float*)carve(SZ128);                       // later xr2
  float* g2  = (float*)carve(SZ128);
  float* lg1 = (float*)carve((size_t)ET * 4 * sizeof(float));
  float* lg2 = (float*)carve((size_t)ET * sizeof(float));
  int* src_s = (int*)carve((size_t)ET * sizeof(int));
  int* dst_s = (int*)carve((size_t)ET * sizeof(int));
  int* cnt   = (int*)carve((size_t)2 * M * sizeof(int));   // counts + cursor
  int* cur   = cnt + M;
  int* offs  = (int*)carve((size_t)(M + 1) * sizeof(int));
  // overlays after GAT phases retire the big buffers:
  float* rf  = xl1;
  float* cf  = (float*)((char*)xl1 + SZ128);
  float* kf  = (float*)((char*)xl1 + 2 * SZ128);
  float* xl2 = hn;
  float* xr2 = h0;
  (void)ws_size; (void)n_in; (void)out_size;

  // CSR by dst
  hipMemsetAsync(cnt, 0, (size_t)2 * M * sizeof(int), stream);
  k_count<<<(ET + 255) / 256, 256, 0, stream>>>(ei, cnt, E0, ET);
  k_scan<<<1, 1024, 0, stream>>>(cnt, offs, M);
  k_scatter<<<(ET + 255) / 256, 256, 0, stream>>>(ei, offs, cur, src_s, dst_s, E0, ET);

  // node pipeline
  k_ln<128, 0><<<M, 128, 0, stream>>>(x, hn, fn_g, fn_b);
  k_dense<128, 128, 16, 1><<<M / 16, 256, 0, stream>>>(hn, W_in, b_in, h0);
  k_dense<128, 512, 4, 0><<<M / 4, 256, 0, stream>>>(h0, Wl1, bl1, xl1);
  k_dense<128, 512, 4, 0><<<M / 4, 256, 0, stream>>>(h0, Wr1, br1, xr1);
  k_logits1<<<(ET + 3) / 4, 256, 0, stream>>>(src_s, dst_s, xl1, xr1, att1, lg1, ET);
  k_agg1<<<M, 256, 0, stream>>>(offs, src_s, lg1, xl1, bg1, g1);
  k_ln<512, 2><<<M, 256, 0, stream>>>(g1, g1, ln1_g, ln1_b);
  k_dense<512, 128, 16, 0><<<M / 16, 256, 0, stream>>>(g1, Wl2, bl2, xl2);
  k_dense<512, 128, 16, 0><<<M / 16, 256, 0, stream>>>(g1, Wr2, br2, xr2);
  k_logits2<<<(ET + 3) / 4, 256, 0, stream>>>(src_s, dst_s, xl2, xr2, att2, lg2, ET);
  k_agg2<<<M, 128, 0, stream>>>(offs, src_s, lg2, xl2, bg2, g2);

  float* out_ret  = (float*)d_out;
  float* out_mov  = out_ret + M;
  float* out_rank = out_ret + 3 * M;
  float* emb      = out_ret + 4 * M;
  k_ln<128, 2><<<M, 128, 0, stream>>>(g2, emb, ln2_g, ln2_b);

  // feature branches
  k_dense<128, 128, 16, 0><<<M / 16, 256, 0, stream>>>(emb, Wrf, brf, rf);
  k_dense<128, 128, 16, 0><<<M / 16, 256, 0, stream>>>(emb, Wcf, bcf, cf);
  k_dense<128, 128, 16, 0><<<M / 16, 256, 0, stream>>>(emb, Wkf, bkf, kf);
  k_ln<128, 1><<<M, 128, 0, stream>>>(rf, rf, rf_g, rf_b);
  k_ln<128, 1><<<M, 128, 0, stream>>>(cf, cf, cf_g, cf_b);
  k_ln<128, 1><<<M, 128, 0, stream>>>(kf, kf, kf_g, kf_b);

  // heads
  k_head_ret<<<M / 4, 256, 0, stream>>>(rf, Wr1h, br1h, Wr2h, br2h, Wr3h, br3h, out_ret);
  k_head_mov<<<M / 4, 256, 0, stream>>>(cf, Wc1h, bc1h, Wc2h, bc2h, out_mov);
  k_head_rank<<<M / 4, 256, 0, stream>>>(kf, Wk1h, bk1h, Wk2h, bk2h, out_rank);
}

// Round 2
// 794.523 us; speedup vs baseline: 1.0305x; 1.0305x over previous
//
#include <hip/hip_runtime.h>
#include <cmath>

#define DEV __device__ __forceinline__

typedef __attribute__((ext_vector_type(8))) unsigned short ushort8v;

DEV float lrelu(float v) { return v > 0.f ? v : 0.2f * v; }
DEV float bf2f(unsigned short u) { return __uint_as_float((unsigned)u << 16); }
DEV unsigned short f2bf(float f) {
  unsigned u = __float_as_uint(f);
  unsigned r = (u + 0x7fffu + ((u >> 16) & 1u)) >> 16;
  return (unsigned short)r;
}

// ---------------- CSR build ----------------
__global__ void k_count(const int* __restrict__ ei, int* __restrict__ counts,
                        int E0, int ET) {
  int e = blockIdx.x * 256 + threadIdx.x;
  if (e >= ET) return;
  int dst = (e < E0) ? ei[E0 + e] : (e - E0);
  atomicAdd(&counts[dst], 1);
}

// single-block 1024-thread scan, 3 barriers
__global__ __launch_bounds__(1024) void k_scan2(const int* __restrict__ counts,
                                                int* __restrict__ offs, int n) {
  int t = threadIdx.x;
  int ch = (n + 1023) >> 10;
  int beg = t * ch, end = min(beg + ch, n);
  int loc = 0;
  for (int i = beg; i < end; ++i) loc += counts[i];
  int lane = t & 63, w = t >> 6;
  int v = loc;
#pragma unroll
  for (int m = 1; m < 64; m <<= 1) {
    int u = __shfl_up(v, m);
    if (lane >= m) v += u;
  }
  __shared__ int wsum[16], wpre[16];
  if (lane == 63) wsum[w] = v;
  __syncthreads();
  if (t < 16) {
    int p = 0;
    for (int i = 0; i < t; ++i) p += wsum[i];
    wpre[t] = p;
  }
  __syncthreads();
  int run = wpre[w] + v - loc;  // exclusive prefix of this thread's chunk
  for (int i = beg; i < end; ++i) { offs[i] = run; run += counts[i]; }
  if (beg < n && end == n) offs[n] = run;
}

__global__ void k_scatter(const int* __restrict__ ei, const int* __restrict__ offs,
                          int* __restrict__ cursor, int* __restrict__ src_s,
                          int* __restrict__ dst_s, int E0, int ET) {
  int e = blockIdx.x * 256 + threadIdx.x;
  if (e >= ET) return;
  int src, dst;
  if (e < E0) { src = ei[e]; dst = ei[E0 + e]; }
  else        { src = e - E0; dst = e - E0; }
  int pos = offs[dst] + atomicAdd(&cursor[dst], 1);
  src_s[pos] = src;
  dst_s[pos] = dst;
}

// ---------------- LayerNorm (+opt act). ACT: 0 none, 1 relu, 2 elu ----------------
template<int C, int ACT>
__global__ void k_ln(const float* in, float* out, const float* g, const float* b) {
  constexpr int T = (C < 256) ? C : 256;
  constexpr int EPT = C / T;
  constexpr int NW = T / 64;
  int row = blockIdx.x, t = threadIdx.x;
  const float* ip = in + (size_t)row * C;
  float v[EPT];
  float s = 0.f, s2 = 0.f;
#pragma unroll
  for (int e = 0; e < EPT; ++e) { float xv = ip[t + e * T]; v[e] = xv; s += xv; s2 += xv * xv; }
#pragma unroll
  for (int m = 1; m <= 32; m <<= 1) { s += __shfl_xor(s, m); s2 += __shfl_xor(s2, m); }
  __shared__ float w1s[NW], w2s[NW];
  if (NW > 1) {
    if ((t & 63) == 0) { w1s[t >> 6] = s; w2s[t >> 6] = s2; }
    __syncthreads();
    s = 0.f; s2 = 0.f;
#pragma unroll
    for (int i = 0; i < NW; ++i) { s += w1s[i]; s2 += w2s[i]; }
  }
  float mu = s * (1.0f / C);
  float var = s2 * (1.0f / C) - mu * mu;
  float rs = rsqrtf(var + 1e-5f);
  float* op = out + (size_t)row * C;
#pragma unroll
  for (int e = 0; e < EPT; ++e) {
    int c = t + e * T;
    float y = (v[e] - mu) * rs * g[c] + b[c];
    if (ACT == 1) y = fmaxf(y, 0.f);
    if (ACT == 2) y = (y > 0.f) ? y : expm1f(y);
    op[c] = y;
  }
}

// ---------------- Dense: C = act(A[M,K] @ W[K,N] + bias), optional bf16 shadow ----------------
template<int K, int N, int RPB, int ACT, bool WB16>
__global__ __launch_bounds__(256) void k_dense(const float* __restrict__ A,
                                               const float* __restrict__ W,
                                               const float* __restrict__ bias,
                                               float* __restrict__ Cc,
                                               unsigned short* __restrict__ Cb) {
  constexpr int NTC = (N < 256) ? N : 256;
  constexpr int NTR = 256 / NTC;
  constexpr int CPT = N / NTC;
  constexpr int RPT = RPB / NTR;
  __shared__ float As[RPB * K];
  int row0 = blockIdx.x * RPB;
  {
    const float4* Ag = reinterpret_cast<const float4*>(A + (size_t)row0 * K);
    float4* As4 = reinterpret_cast<float4*>(As);
    for (int i = threadIdx.x; i < RPB * K / 4; i += 256) As4[i] = Ag[i];
  }
  __syncthreads();
  int tc = threadIdx.x % NTC;
  int tr = threadIdx.x / NTC;
  float acc[RPT][CPT];
#pragma unroll
  for (int r = 0; r < RPT; ++r)
#pragma unroll
    for (int j = 0; j < CPT; ++j) acc[r][j] = 0.f;
  for (int k = 0; k < K; k += 4) {
    float w0[CPT], w1[CPT], w2[CPT], w3[CPT];
#pragma unroll
    for (int j = 0; j < CPT; ++j) {
      int c = tc + j * NTC;
      w0[j] = W[(k + 0) * N + c];
      w1[j] = W[(k + 1) * N + c];
      w2[j] = W[(k + 2) * N + c];
      w3[j] = W[(k + 3) * N + c];
    }
#pragma unroll
    for (int r = 0; r < RPT; ++r) {
      float4 av = *reinterpret_cast<const float4*>(&As[(tr + r * NTR) * K + k]);
#pragma unroll
      for (int j = 0; j < CPT; ++j) {
        acc[r][j] = fmaf(av.x, w0[j], acc[r][j]);
        acc[r][j] = fmaf(av.y, w1[j], acc[r][j]);
        acc[r][j] = fmaf(av.z, w2[j], acc[r][j]);
        acc[r][j] = fmaf(av.w, w3[j], acc[r][j]);
      }
    }
  }
#pragma unroll
  for (int r = 0; r < RPT; ++r) {
    int row = row0 + tr + r * NTR;
#pragma unroll
    for (int j = 0; j < CPT; ++j) {
      int c = tc + j * NTC;
      float v = acc[r][j] + bias[c];
      if (ACT == 1) v = fmaxf(v, 0.f);
      Cc[(size_t)row * N + c] = v;
      if (WB16) Cb[(size_t)row * N + c] = f2bf(v);
    }
  }
}

// ---------------- GATv2 edge logits, layer 1 (4 heads x 128), bf16 gathers ----------------
__global__ __launch_bounds__(256) void k_logits1(const int* __restrict__ src_s,
                                                 const int* __restrict__ dst_s,
                                                 const unsigned short* __restrict__ xl,
                                                 const unsigned short* __restrict__ xr,
                                                 const float* __restrict__ att,
                                                 float* __restrict__ logit, int ET) {
  int wid = threadIdx.x >> 6, lane = threadIdx.x & 63;
  int p = blockIdx.x * 4 + wid;
  if (p >= ET) return;
  int sn = src_s[p], dn = dst_s[p];
  const ushort8v* xlp = reinterpret_cast<const ushort8v*>(xl + (size_t)sn * 512);
  const ushort8v* xrp = reinterpret_cast<const ushort8v*>(xr + (size_t)dn * 512);
  ushort8v a = xlp[lane], c = xrp[lane];
  const float* atp = att + lane * 8;  // att flat [4*128], lane covers one head's slice
  float s = 0.f;
#pragma unroll
  for (int j = 0; j < 8; ++j)
    s = fmaf(atp[j], lrelu(bf2f(a[j]) + bf2f(c[j])), s);
#pragma unroll
  for (int m = 1; m <= 8; m <<= 1) s += __shfl_xor(s, m);
  if ((lane & 15) == 0) logit[(size_t)p * 4 + (lane >> 4)] = s;
}

// ---------------- GATv2 edge logits, layer 2 (1 head x 128), bf16 gathers ----------------
__global__ __launch_bounds__(256) void k_logits2(const int* __restrict__ src_s,
                                                 const int* __restrict__ dst_s,
                                                 const unsigned short* __restrict__ xl,
                                                 const unsigned short* __restrict__ xr,
                                                 const float* __restrict__ att,
                                                 float* __restrict__ logit, int ET) {
  int wid = threadIdx.x >> 6, lane = threadIdx.x & 63;
  int p = blockIdx.x * 4 + wid;
  if (p >= ET) return;
  int sn = src_s[p], dn = dst_s[p];
  unsigned ua = reinterpret_cast<const unsigned*>(xl + (size_t)sn * 128)[lane];
  unsigned uc = reinterpret_cast<const unsigned*>(xr + (size_t)dn * 128)[lane];
  float2 w = reinterpret_cast<const float2*>(att)[lane];
  float a0 = __uint_as_float(ua << 16), a1 = __uint_as_float(ua & 0xffff0000u);
  float c0 = __uint_as_float(uc << 16), c1 = __uint_as_float(uc & 0xffff0000u);
  float s = w.x * lrelu(a0 + c0) + w.y * lrelu(a1 + c1);
#pragma unroll
  for (int m = 1; m <= 32; m <<= 1) s += __shfl_xor(s, m);
  if (lane == 0) logit[p] = s;
}

// ---------------- GAT1 aggregate: block per dst node, 512 channels ----------------
__global__ __launch_bounds__(256) void k_agg1(const int* __restrict__ offs,
                                              const int* __restrict__ src_s,
                                              const float* __restrict__ logit,
                                              const float* __restrict__ xl,
                                              const float* __restrict__ bg,
                                              float* __restrict__ outg) {
  int n = blockIdx.x;
  int st = offs[n], en = offs[n + 1];
  int t = threadIdx.x;
  __shared__ float sm[4], sinv[4];
  __shared__ float wl[256];
  __shared__ int srcl[64];
  {  // per-head max & sum(exp), one wave per head
    int h = t >> 6, l = t & 63;
    float mx = -3.0e38f;
    for (int i = l; i < en - st; i += 64) mx = fmaxf(mx, logit[(size_t)(st + i) * 4 + h]);
#pragma unroll
    for (int m = 1; m <= 32; m <<= 1) mx = fmaxf(mx, __shfl_xor(mx, m));
    float se = 0.f;
    for (int i = l; i < en - st; i += 64) se += expf(logit[(size_t)(st + i) * 4 + h] - mx);
#pragma unroll
    for (int m = 1; m <= 32; m <<= 1) se += __shfl_xor(se, m);
    if (l == 0) { sm[h] = mx; sinv[h] = 1.0f / (se + 1e-16f); }
  }
  __syncthreads();
  float acc0 = 0.f, acc1 = 0.f;
  int h0 = t >> 7;  // head of channel t (0/1); channel t+256 is head h0+2
  for (int base = st; base < en; base += 64) {
    int len = min(64, en - base);
    if (t < len * 4) {
      int i = t >> 2, h = t & 3;
      wl[t] = expf(logit[(size_t)(base + i) * 4 + h] - sm[h]) * sinv[h];
    }
    if (t < len) srcl[t] = src_s[base + t];
    __syncthreads();
    for (int i = 0; i < len; ++i) {
      const float* xp = xl + (size_t)srcl[i] * 512;
      acc0 += wl[i * 4 + h0]     * xp[t];
      acc1 += wl[i * 4 + h0 + 2] * xp[t + 256];
    }
    __syncthreads();
  }
  float* op = outg + (size_t)n * 512;
  op[t]       = acc0 + bg[t];
  op[t + 256] = acc1 + bg[t + 256];
}

// ---------------- GAT2 aggregate: block per dst node, 128 channels ----------------
__global__ __launch_bounds__(128) void k_agg2(const int* __restrict__ offs,
                                              const int* __restrict__ src_s,
                                              const float* __restrict__ logit,
                                              const float* __restrict__ xl,
                                              const float* __restrict__ bg,
                                              float* __restrict__ outg) {
  int n = blockIdx.x;
  int st = offs[n], en = offs[n + 1];
  int t = threadIdx.x;
  __shared__ float sm1, sinv1;
  __shared__ float wl[64];
  __shared__ int srcl[64];
  if (t < 64) {
    float mx = -3.0e38f;
    for (int i = t; i < en - st; i += 64) mx = fmaxf(mx, logit[st + i]);
#pragma unroll
    for (int m = 1; m <= 32; m <<= 1) mx = fmaxf(mx, __shfl_xor(mx, m));
    float se = 0.f;
    for (int i = t; i < en - st; i += 64) se += expf(logit[st + i] - mx);
#pragma unroll
    for (int m = 1; m <= 32; m <<= 1) se += __shfl_xor(se, m);
    if (t == 0) { sm1 = mx; sinv1 = 1.0f / (se + 1e-16f); }
  }
  __syncthreads();
  float acc = 0.f;
  for (int base = st; base < en; base += 64) {
    int len = min(64, en - base);
    if (t < len) { wl[t] = expf(logit[base + t] - sm1) * sinv1; srcl[t] = src_s[base + t]; }
    __syncthreads();
    for (int i = 0; i < len; ++i) acc += wl[i] * xl[(size_t)srcl[i] * 128 + t];
    __syncthreads();
  }
  outg[(size_t)n * 128 + t] = acc + bg[t];
}

// ---------------- Fused MLP heads (wave per row) ----------------
__global__ __launch_bounds__(256) void k_head_ret(const float* __restrict__ in,
    const float* __restrict__ W1, const float* __restrict__ b1,
    const float* __restrict__ W2, const float* __restrict__ b2,
    const float* __restrict__ W3, const float* __restrict__ b3,
    float* __restrict__ out) {
  __shared__ float sh[4][224];
  int wid = threadIdx.x >> 6, lane = threadIdx.x & 63;
  int row = blockIdx.x * 4 + wid;
  const float2* rp = reinterpret_cast<const float2*>(in + (size_t)row * 128);
  float2 f2 = rp[lane];
  sh[wid][2 * lane] = f2.x;
  sh[wid][2 * lane + 1] = f2.y;
  __syncthreads();
  float a = b1[lane];
#pragma unroll 8
  for (int k = 0; k < 128; ++k) a = fmaf(sh[wid][k], W1[k * 64 + lane], a);
  sh[wid][128 + lane] = fmaxf(a, 0.f);
  __syncthreads();
  if (lane < 32) {
    float a2 = b2[lane];
#pragma unroll 8
    for (int k = 0; k < 64; ++k) a2 = fmaf(sh[wid][128 + k], W2[k * 32 + lane], a2);
    sh[wid][192 + lane] = fmaxf(a2, 0.f);
  }
  __syncthreads();
  if (lane == 0) {
    float a3 = b3[0];
#pragma unroll
    for (int k = 0; k < 32; ++k) a3 = fmaf(sh[wid][192 + k], W3[k], a3);
    out[row] = tanhf(a3) * 0.1f;
  }
}

__global__ __launch_bounds__(256) void k_head_mov(const float* __restrict__ in,
    const float* __restrict__ W1, const float* __restrict__ b1,
    const float* __restrict__ W2, const float* __restrict__ b2,
    float* __restrict__ out) {
  __shared__ float sh[4][192];
  int wid = threadIdx.x >> 6, lane = threadIdx.x & 63;
  int row = blockIdx.x * 4 + wid;
  const float2* rp = reinterpret_cast<const float2*>(in + (size_t)row * 128);
  float2 f2 = rp[lane];
  sh[wid][2 * lane] = f2.x;
  sh[wid][2 * lane + 1] = f2.y;
  __syncthreads();
  float a = b1[lane];
#pragma unroll 8
  for (int k = 0; k < 128; ++k) a = fmaf(sh[wid][k], W1[k * 64 + lane], a);
  sh[wid][128 + lane] = fmaxf(a, 0.f);
  __syncthreads();
  if (lane < 2) {
    float a2 = b2[lane];
#pragma unroll 8
    for (int k = 0; k < 64; ++k) a2 = fmaf(sh[wid][128 + k], W2[k * 2 + lane], a2);
    out[(size_t)row * 2 + lane] = a2;
  }
}

__global__ __launch_bounds__(256) void k_head_rank(const float* __restrict__ in,
    const float* __restrict__ W1, const float* __restrict__ b1,
    const float* __restrict__ W2, const float* __restrict__ b2,
    float* __restrict__ out) {
  __shared__ float sh[4][192];
  int wid = threadIdx.x >> 6, lane = threadIdx.x & 63;
  int row = blockIdx.x * 4 + wid;
  const float2* rp = reinterpret_cast<const float2*>(in + (size_t)row * 128);
  float2 f2 = rp[lane];
  sh[wid][2 * lane] = f2.x;
  sh[wid][2 * lane + 1] = f2.y;
  __syncthreads();
  float a = b1[lane];
#pragma unroll 8
  for (int k = 0; k < 128; ++k) a = fmaf(sh[wid][k], W1[k * 64 + lane], a);
  sh[wid][128 + lane] = fmaxf(a, 0.f);
  __syncthreads();
  if (lane == 0) {
    float a2 = b2[0];
#pragma unroll 8
    for (int k = 0; k < 64; ++k) a2 = fmaf(sh[wid][128 + k], W2[k], a2);
    out[row] = 1.0f / (1.0f + expf(-a2));
  }
}

// ---------------- launch ----------------
extern "C" void kernel_launch(void* const* d_in, const int* in_sizes, int n_in,
                              void* d_out, int out_size, void* d_ws, size_t ws_size,
                              hipStream_t stream) {
  const float* x     = (const float*)d_in[0];
  const int*   ei    = (const int*)  d_in[1];
  const float* fn_g  = (const float*)d_in[2];
  const float* fn_b  = (const float*)d_in[3];
  const float* W_in  = (const float*)d_in[4];
  const float* b_in  = (const float*)d_in[5];
  const float* Wl1   = (const float*)d_in[6];
  const float* bl1   = (const float*)d_in[7];
  const float* Wr1   = (const float*)d_in[8];
  const float* br1   = (const float*)d_in[9];
  const float* att1  = (const float*)d_in[10];
  const float* bg1   = (const float*)d_in[11];
  const float* Wl2   = (const float*)d_in[12];
  const float* bl2   = (const float*)d_in[13];
  const float* Wr2   = (const float*)d_in[14];
  const float* br2   = (const float*)d_in[15];
  const float* att2  = (const float*)d_in[16];
  const float* bg2   = (const float*)d_in[17];
  const float* ln1_g = (const float*)d_in[18];
  const float* ln1_b = (const float*)d_in[19];
  const float* ln2_g = (const float*)d_in[20];
  const float* ln2_b = (const float*)d_in[21];
  const float* Wrf   = (const float*)d_in[22];
  const float* brf   = (const float*)d_in[23];
  const float* rf_g  = (const float*)d_in[24];
  const float* rf_b  = (const float*)d_in[25];
  const float* Wcf   = (const float*)d_in[26];
  const float* bcf   = (const float*)d_in[27];
  const float* cf_g  = (const float*)d_in[28];
  const float* cf_b  = (const float*)d_in[29];
  const float* Wkf   = (const float*)d_in[30];
  const float* bkf   = (const float*)d_in[31];
  const float* kf_g  = (const float*)d_in[32];
  const float* kf_b  = (const float*)d_in[33];
  const float* Wr1h  = (const float*)d_in[34];
  const float* br1h  = (const float*)d_in[35];
  const float* Wr2h  = (const float*)d_in[36];
  const float* br2h  = (const float*)d_in[37];
  const float* Wr3h  = (const float*)d_in[38];
  const float* br3h  = (const float*)d_in[39];
  const float* Wc1h  = (const float*)d_in[40];
  const float* bc1h  = (const float*)d_in[41];
  const float* Wc2h  = (const float*)d_in[42];
  const float* bc2h  = (const float*)d_in[43];
  const float* Wk1h  = (const float*)d_in[44];
  const float* bk1h  = (const float*)d_in[45];
  const float* Wk2h  = (const float*)d_in[46];
  const float* bk2h  = (const float*)d_in[47];

  const int M  = in_sizes[0] / 128;   // 20000
  const int E0 = in_sizes[1] / 2;     // 320000
  const int ET = E0 + M;              // 340000

  char* base = (char*)d_ws;
  size_t off = 0;
  auto carve = [&](size_t bytes) -> char* {
    off = (off + 255) & ~(size_t)255;
    char* p = base + off;
    off += bytes;
    return p;
  };
  const size_t SZ512 = (size_t)M * 512 * sizeof(float);
  const size_t SZ128 = (size_t)M * 128 * sizeof(float);
  float* xl1 = (float*)carve(SZ512);
  float* xr1 = (float*)carve(SZ512);
  float* g1  = (float*)carve(SZ512);                       // agg1 out -> ln1 in place
  float* hn  = (float*)carve(SZ128);                       // later xl2
  float* h0  = (float*)carve(SZ128);                       // later xr2
  float* g2  = (float*)carve(SZ128);
  float* lg1 = (float*)carve((size_t)ET * 4 * sizeof(float));
  float* lg2 = (float*)carve((size_t)ET * sizeof(float));
  int* src_s = (int*)carve((size_t)ET * sizeof(int));
  int* dst_s = (int*)carve((size_t)ET * sizeof(int));
  int* cnt   = (int*)carve((size_t)2 * M * sizeof(int));   // counts + cursor
  int* cur   = cnt + M;
  int* offs  = (int*)carve((size_t)(M + 1) * sizeof(int));
  // temporal overlays:
  //  - bf16 shadows of xl1/xr1 live in g1 (g1 not written until agg1, after logits1)
  unsigned short* xl1h = (unsigned short*)g1;
  unsigned short* xr1h = xl1h + (size_t)M * 512;
  //  - bf16 shadows of xl2/xr2 live in xr1 (xr1 dead after logits1)
  unsigned short* xl2h = (unsigned short*)xr1;
  unsigned short* xr2h = xl2h + (size_t)M * 128;
  //  - feature branches live in xl1 (dead after agg1)
  float* rf  = xl1;
  float* cf  = (float*)((char*)xl1 + SZ128);
  float* kf  = (float*)((char*)xl1 + 2 * SZ128);
  float* xl2 = hn;
  float* xr2 = h0;
  (void)ws_size; (void)n_in; (void)out_size;

  // CSR by dst
  hipMemsetAsync(cnt, 0, (size_t)2 * M * sizeof(int), stream);
  k_count<<<(ET + 255) / 256, 256, 0, stream>>>(ei, cnt, E0, ET);
  k_scan2<<<1, 1024, 0, stream>>>(cnt, offs, M);
  k_scatter<<<(ET + 255) / 256, 256, 0, stream>>>(ei, offs, cur, src_s, dst_s, E0, ET);

  // node pipeline
  k_ln<128, 0><<<M, 128, 0, stream>>>(x, hn, fn_g, fn_b);
  k_dense<128, 128, 16, 1, false><<<M / 16, 256, 0, stream>>>(hn, W_in, b_in, h0, nullptr);
  k_dense<128, 512, 16, 0, true><<<M / 16, 256, 0, stream>>>(h0, Wl1, bl1, xl1, xl1h);
  k_dense<128, 512, 16, 0, true><<<M / 16, 256, 0, stream>>>(h0, Wr1, br1, xr1, xr1h);
  k_logits1<<<(ET + 3) / 4, 256, 0, stream>>>(src_s, dst_s, xl1h, xr1h, att1, lg1, ET);
  k_agg1<<<M, 256, 0, stream>>>(offs, src_s, lg1, xl1, bg1, g1);
  k_ln<512, 2><<<M, 256, 0, stream>>>(g1, g1, ln1_g, ln1_b);
  k_dense<512, 128, 16, 0, true><<<M / 16, 256, 0, stream>>>(g1, Wl2, bl2, xl2, xl2h);
  k_dense<512, 128, 16, 0, true><<<M / 16, 256, 0, stream>>>(g1, Wr2, br2, xr2, xr2h);
  k_logits2<<<(ET + 3) / 4, 256, 0, stream>>>(src_s, dst_s, xl2h, xr2h, att2, lg2, ET);
  k_agg2<<<M, 128, 0, stream>>>(offs, src_s, lg2, xl2, bg2, g2);

  float* out_ret  = (float*)d_out;
  float* out_mov  = out_ret + M;
  float* out_rank = out_ret + 3 * M;
  float* emb      = out_ret + 4 * M;
  k_ln<128, 2><<<M, 128, 0, stream>>>(g2, emb, ln2_g, ln2_b);

  // feature branches
  k_dense<128, 128, 16, 0, false><<<M / 16, 256, 0, stream>>>(emb, Wrf, brf, rf, nullptr);
  k_dense<128, 128, 16, 0, false><<<M / 16, 256, 0, stream>>>(emb, Wcf, bcf, cf, nullptr);
  k_dense<128, 128, 16, 0, false><<<M / 16, 256, 0, stream>>>(emb, Wkf, bkf, kf, nullptr);
  k_ln<128, 1><<<M, 128, 0, stream>>>(rf, rf, rf_g, rf_b);
  k_ln<128, 1><<<M, 128, 0, stream>>>(cf, cf, cf_g, cf_b);
  k_ln<128, 1><<<M, 128, 0, stream>>>(kf, kf, kf_g, kf_b);

  // heads
  k_head_ret<<<M / 4, 256, 0, stream>>>(rf, Wr1h, br1h, Wr2h, br2h, Wr3h, br3h, out_ret);
  k_head_mov<<<M / 4, 256, 0, stream>>>(cf, Wc1h, bc1h, Wc2h, bc2h, out_mov);
  k_head_rank<<<M / 4, 256, 0, stream>>>(kf, Wk1h, bk1h, Wk2h, bk2h, out_rank);
}

// Round 3
// 493.964 us; speedup vs baseline: 1.6575x; 1.6085x over previous
//
#include <hip/hip_runtime.h>
#include <cmath>

#define DEV __device__ __forceinline__

typedef __attribute__((ext_vector_type(8))) unsigned short ushort8v;
typedef __attribute__((ext_vector_type(8))) short short8v;
typedef __attribute__((ext_vector_type(4))) float f32x4;

DEV float lrelu(float v) { return v > 0.f ? v : 0.2f * v; }
DEV float elu(float v) { return v > 0.f ? v : expm1f(v); }
DEV float bf2f(unsigned short u) { return __uint_as_float((unsigned)u << 16); }
DEV unsigned short f2bf(float f) {
  unsigned u = __float_as_uint(f);
  unsigned r = (u + 0x7fffu + ((u >> 16) & 1u)) >> 16;
  return (unsigned short)r;
}

// ---------------- CSR build ----------------
__global__ void k_count(const int* __restrict__ ei, int* __restrict__ counts,
                        int E0, int ET) {
  int e = blockIdx.x * 256 + threadIdx.x;
  if (e >= ET) return;
  int dst = (e < E0) ? ei[E0 + e] : (e - E0);
  atomicAdd(&counts[dst], 1);
}

__global__ __launch_bounds__(1024) void k_scan2(const int* __restrict__ counts,
                                                int* __restrict__ offs, int n) {
  int t = threadIdx.x;
  int ch = (n + 1023) >> 10;
  int beg = t * ch, end = min(beg + ch, n);
  int loc = 0;
  for (int i = beg; i < end; ++i) loc += counts[i];
  int lane = t & 63, w = t >> 6;
  int v = loc;
#pragma unroll
  for (int m = 1; m < 64; m <<= 1) {
    int u = __shfl_up(v, m);
    if (lane >= m) v += u;
  }
  __shared__ int wsum[16], wpre[16];
  if (lane == 63) wsum[w] = v;
  __syncthreads();
  if (t < 16) {
    int p = 0;
    for (int i = 0; i < t; ++i) p += wsum[i];
    wpre[t] = p;
  }
  __syncthreads();
  int run = wpre[w] + v - loc;
  for (int i = beg; i < end; ++i) { offs[i] = run; run += counts[i]; }
  if (beg < n && end == n) offs[n] = run;
}

__global__ void k_scatter(const int* __restrict__ ei, const int* __restrict__ offs,
                          int* __restrict__ cursor, int* __restrict__ src_s,
                          int* __restrict__ dst_s, int E0, int ET) {
  int e = blockIdx.x * 256 + threadIdx.x;
  if (e >= ET) return;
  int src, dst;
  if (e < E0) { src = ei[e]; dst = ei[E0 + e]; }
  else        { src = e - E0; dst = e - E0; }
  int pos = offs[dst] + atomicAdd(&cursor[dst], 1);
  src_s[pos] = src;
  dst_s[pos] = dst;
}

// ---------------- Weight pack into MFMA B-fragment order ----------------
// Wp flat idx = (((tile*KB + kb)*64 + lane)*8 + j)
// maps to W[k*N + col], k = kb*32 + (lane>>4)*8 + j, col = tile*16 + (lane&15)
__global__ void k_pack(const float* __restrict__ W, unsigned short* __restrict__ Wp,
                       int K, int N) {
  int idx = blockIdx.x * 256 + threadIdx.x;
  if (idx >= N * K) return;
  int j = idx & 7, l = (idx >> 3) & 63, r = idx >> 9;
  int KB = K / 32;
  int tile = r / KB, kb = r - tile * KB;
  int k = kb * 32 + (l >> 4) * 8 + j;
  int col = tile * 16 + (l & 15);
  Wp[idx] = f2bf(W[(size_t)k * N + col]);
}

// ---------------- MFMA GEMM: C[M,N] = act(A[M,K](bf16) @ W + bias) ----------------
template<int K, int N, int ACT, bool OF32, bool OB16>
__global__ __launch_bounds__(256) void k_mfma(const unsigned short* __restrict__ A,
                                              const unsigned short* __restrict__ Wp,
                                              const float* __restrict__ bias,
                                              float* __restrict__ Cf,
                                              unsigned short* __restrict__ Cb) {
  constexpr int KB = K / 32;   // k-blocks of 32
  constexpr int TPW = N / 64;  // 16-col tiles per wave (4 waves cover N)
  __shared__ short As[KB * 64 * 8];  // [kb][lane][8] fragment order
  int row0 = blockIdx.x * 16;
  int t = threadIdx.x, lane = t & 63, w = t >> 6;
  // stage A panel (16 rows x K) into fragment-ordered LDS
  for (int idx = t; idx < KB * 64; idx += 256) {
    int kb = idx >> 6, l = idx & 63;
    const short8v* sp = reinterpret_cast<const short8v*>(
        A + (size_t)(row0 + (l & 15)) * K + kb * 32 + (l >> 4) * 8);
    reinterpret_cast<short8v*>(As)[idx] = *sp;
  }
  __syncthreads();
  f32x4 acc[TPW];
#pragma unroll
  for (int j = 0; j < TPW; ++j) acc[j] = f32x4{0.f, 0.f, 0.f, 0.f};
  const short8v* Bp = reinterpret_cast<const short8v*>(Wp);
  for (int kb = 0; kb < KB; ++kb) {
    short8v a = reinterpret_cast<const short8v*>(As)[kb * 64 + lane];
#pragma unroll
    for (int j = 0; j < TPW; ++j) {
      int tile = w * TPW + j;
      short8v b = Bp[(tile * KB + kb) * 64 + lane];
      acc[j] = __builtin_amdgcn_mfma_f32_16x16x32_bf16(a, b, acc[j], 0, 0, 0);
    }
  }
#pragma unroll
  for (int j = 0; j < TPW; ++j) {
    int col = (w * TPW + j) * 16 + (lane & 15);
    float bs = bias[col];
#pragma unroll
    for (int r = 0; r < 4; ++r) {
      int row = row0 + (lane >> 4) * 4 + r;
      float v = acc[j][r] + bs;
      if (ACT == 1) v = fmaxf(v, 0.f);
      if (OF32) Cf[(size_t)row * N + col] = v;
      if (OB16) Cb[(size_t)row * N + col] = f2bf(v);
    }
  }
}

// ---------------- LayerNorm (+opt act). OUT16: write bf16 instead of f32 ----------------
template<int C, int ACT, bool OUT16>
__global__ void k_ln(const float* in, void* out, const float* g, const float* b) {
  constexpr int T = (C < 256) ? C : 256;
  constexpr int EPT = C / T;
  constexpr int NW = T / 64;
  int row = blockIdx.x, t = threadIdx.x;
  const float* ip = in + (size_t)row * C;
  float v[EPT];
  float s = 0.f, s2 = 0.f;
#pragma unroll
  for (int e = 0; e < EPT; ++e) { float xv = ip[t + e * T]; v[e] = xv; s += xv; s2 += xv * xv; }
#pragma unroll
  for (int m = 1; m <= 32; m <<= 1) { s += __shfl_xor(s, m); s2 += __shfl_xor(s2, m); }
  __shared__ float w1s[NW], w2s[NW];
  if (NW > 1) {
    if ((t & 63) == 0) { w1s[t >> 6] = s; w2s[t >> 6] = s2; }
    __syncthreads();
    s = 0.f; s2 = 0.f;
#pragma unroll
    for (int i = 0; i < NW; ++i) { s += w1s[i]; s2 += w2s[i]; }
  }
  float mu = s * (1.0f / C);
  float var = s2 * (1.0f / C) - mu * mu;
  float rs = rsqrtf(var + 1e-5f);
#pragma unroll
  for (int e = 0; e < EPT; ++e) {
    int c = t + e * T;
    float y = (v[e] - mu) * rs * g[c] + b[c];
    if (ACT == 1) y = fmaxf(y, 0.f);
    if (ACT == 2) y = elu(y);
    if (OUT16) ((unsigned short*)out)[(size_t)row * C + c] = f2bf(y);
    else       ((float*)out)[(size_t)row * C + c] = y;
  }
}

// ---------------- GATv2 edge logits, layer 1 (4 heads x 128), bf16 gathers ----------------
__global__ __launch_bounds__(256) void k_logits1(const int* __restrict__ src_s,
                                                 const int* __restrict__ dst_s,
                                                 const unsigned short* __restrict__ xl,
                                                 const unsigned short* __restrict__ xr,
                                                 const float* __restrict__ att,
                                                 float* __restrict__ logit, int ET) {
  int wid = threadIdx.x >> 6, lane = threadIdx.x & 63;
  int p = blockIdx.x * 4 + wid;
  if (p >= ET) return;
  int sn = src_s[p], dn = dst_s[p];
  const ushort8v* xlp = reinterpret_cast<const ushort8v*>(xl + (size_t)sn * 512);
  const ushort8v* xrp = reinterpret_cast<const ushort8v*>(xr + (size_t)dn * 512);
  ushort8v a = xlp[lane], c = xrp[lane];
  const float* atp = att + lane * 8;
  float s = 0.f;
#pragma unroll
  for (int j = 0; j < 8; ++j)
    s = fmaf(atp[j], lrelu(bf2f(a[j]) + bf2f(c[j])), s);
#pragma unroll
  for (int m = 1; m <= 8; m <<= 1) s += __shfl_xor(s, m);
  if ((lane & 15) == 0) logit[(size_t)p * 4 + (lane >> 4)] = s;
}

// ---------------- GATv2 edge logits, layer 2 (1 head x 128), bf16 gathers ----------------
__global__ __launch_bounds__(256) void k_logits2(const int* __restrict__ src_s,
                                                 const int* __restrict__ dst_s,
                                                 const unsigned short* __restrict__ xl,
                                                 const unsigned short* __restrict__ xr,
                                                 const float* __restrict__ att,
                                                 float* __restrict__ logit, int ET) {
  int wid = threadIdx.x >> 6, lane = threadIdx.x & 63;
  int p = blockIdx.x * 4 + wid;
  if (p >= ET) return;
  int sn = src_s[p], dn = dst_s[p];
  unsigned ua = reinterpret_cast<const unsigned*>(xl + (size_t)sn * 128)[lane];
  unsigned uc = reinterpret_cast<const unsigned*>(xr + (size_t)dn * 128)[lane];
  float2 w = reinterpret_cast<const float2*>(att)[lane];
  float a0 = __uint_as_float(ua << 16), a1 = __uint_as_float(ua & 0xffff0000u);
  float c0 = __uint_as_float(uc << 16), c1 = __uint_as_float(uc & 0xffff0000u);
  float s = w.x * lrelu(a0 + c0) + w.y * lrelu(a1 + c1);
#pragma unroll
  for (int m = 1; m <= 32; m <<= 1) s += __shfl_xor(s, m);
  if (lane == 0) logit[p] = s;
}

// ---------------- GAT1 aggregate + LN1 + elu fused; bf16 in, bf16 out ----------------
__global__ __launch_bounds__(256) void k_agg1(const int* __restrict__ offs,
                                              const int* __restrict__ src_s,
                                              const float* __restrict__ logit,
                                              const unsigned* __restrict__ xlh,  // [M][256] bf16-pairs
                                              const float* __restrict__ bg,
                                              const float* __restrict__ lg,
                                              const float* __restrict__ lb,
                                              unsigned* __restrict__ outh) {     // [M][256] bf16-pairs
  int n = blockIdx.x;
  int st = offs[n], en = offs[n + 1];
  int t = threadIdx.x;
  __shared__ float sm[4], sinv[4];
  {
    int h = t >> 6, l = t & 63;
    float mx = -3.0e38f;
    for (int i = l; i < en - st; i += 64) mx = fmaxf(mx, logit[(size_t)(st + i) * 4 + h]);
#pragma unroll
    for (int m = 1; m <= 32; m <<= 1) mx = fmaxf(mx, __shfl_xor(mx, m));
    float se = 0.f;
    for (int i = l; i < en - st; i += 64) se += expf(logit[(size_t)(st + i) * 4 + h] - mx);
#pragma unroll
    for (int m = 1; m <= 32; m <<= 1) se += __shfl_xor(se, m);
    if (l == 0) { sm[h] = mx; sinv[h] = 1.0f / (se + 1e-16f); }
  }
  __syncthreads();
  __shared__ float wl[256];
  __shared__ int srcl[64];
  float acc0 = 0.f, acc1 = 0.f;
  int hh = t >> 6;  // head of channels 2t, 2t+1
  for (int base = st; base < en; base += 64) {
    int len = min(64, en - base);
    if (t < len * 4) {
      int i = t >> 2, h = t & 3;
      wl[t] = expf(logit[(size_t)(base + i) * 4 + h] - sm[h]) * sinv[h];
    }
    if (t < len) srcl[t] = src_s[base + t];
    __syncthreads();
#pragma unroll 4
    for (int i = 0; i < len; ++i) {
      unsigned u = xlh[(size_t)srcl[i] * 256 + t];
      float wv = wl[i * 4 + hh];
      acc0 = fmaf(wv, __uint_as_float(u << 16), acc0);
      acc1 = fmaf(wv, __uint_as_float(u & 0xffff0000u), acc1);
    }
    __syncthreads();
  }
  float v0 = acc0 + bg[2 * t];
  float v1 = acc1 + bg[2 * t + 1];
  // fused LN over 512 channels
  float s = v0 + v1, s2 = v0 * v0 + v1 * v1;
#pragma unroll
  for (int m = 1; m <= 32; m <<= 1) { s += __shfl_xor(s, m); s2 += __shfl_xor(s2, m); }
  __shared__ float r1[4], r2[4];
  if ((t & 63) == 0) { r1[t >> 6] = s; r2[t >> 6] = s2; }
  __syncthreads();
  s = r1[0] + r1[1] + r1[2] + r1[3];
  s2 = r2[0] + r2[1] + r2[2] + r2[3];
  float mu = s * (1.0f / 512.0f);
  float var = s2 * (1.0f / 512.0f) - mu * mu;
  float rsd = rsqrtf(var + 1e-5f);
  float y0 = elu((v0 - mu) * rsd * lg[2 * t] + lb[2 * t]);
  float y1 = elu((v1 - mu) * rsd * lg[2 * t + 1] + lb[2 * t + 1]);
  outh[(size_t)n * 256 + t] = (unsigned)f2bf(y0) | ((unsigned)f2bf(y1) << 16);
}

// ---------------- GAT2 aggregate + LN2 + elu fused; writes emb f32 + bf16 ----------------
__global__ __launch_bounds__(128) void k_agg2(const int* __restrict__ offs,
                                              const int* __restrict__ src_s,
                                              const float* __restrict__ logit,
                                              const unsigned short* __restrict__ xlh,  // [M][128] bf16
                                              const float* __restrict__ bg,
                                              const float* __restrict__ lg,
                                              const float* __restrict__ lb,
                                              float* __restrict__ emb,
                                              unsigned short* __restrict__ embh) {
  int n = blockIdx.x;
  int st = offs[n], en = offs[n + 1];
  int t = threadIdx.x, lane = t & 63, w = t >> 6;
  __shared__ float sm1, sinv1, pm[2], ps[2];
  {
    float mx = -3.0e38f;
    for (int i = t; i < en - st; i += 128) mx = fmaxf(mx, logit[st + i]);
#pragma unroll
    for (int m = 1; m <= 32; m <<= 1) mx = fmaxf(mx, __shfl_xor(mx, m));
    if (lane == 0) pm[w] = mx;
    __syncthreads();
    mx = fmaxf(pm[0], pm[1]);
    float se = 0.f;
    for (int i = t; i < en - st; i += 128) se += expf(logit[st + i] - mx);
#pragma unroll
    for (int m = 1; m <= 32; m <<= 1) se += __shfl_xor(se, m);
    if (lane == 0) ps[w] = se;
    __syncthreads();
    if (t == 0) { sm1 = mx; sinv1 = 1.0f / (ps[0] + ps[1] + 1e-16f); }
  }
  __syncthreads();
  __shared__ float wl[64];
  __shared__ int srcl[64];
  float acc = 0.f;
  for (int base = st; base < en; base += 64) {
    int len = min(64, en - base);
    if (t < len) { wl[t] = expf(logit[base + t] - sm1) * sinv1; srcl[t] = src_s[base + t]; }
    __syncthreads();
#pragma unroll 4
    for (int i = 0; i < len; ++i)
      acc = fmaf(wl[i], bf2f(xlh[(size_t)srcl[i] * 128 + t]), acc);
    __syncthreads();
  }
  float v = acc + bg[t];
  float s = v, s2 = v * v;
#pragma unroll
  for (int m = 1; m <= 32; m <<= 1) { s += __shfl_xor(s, m); s2 += __shfl_xor(s2, m); }
  __shared__ float r1[2], r2[2];
  if (lane == 0) { r1[w] = s; r2[w] = s2; }
  __syncthreads();
  s = r1[0] + r1[1];
  s2 = r2[0] + r2[1];
  float mu = s * (1.0f / 128.0f);
  float var = s2 * (1.0f / 128.0f) - mu * mu;
  float rsd = rsqrtf(var + 1e-5f);
  float y = elu((v - mu) * rsd * lg[t] + lb[t]);
  emb[(size_t)n * 128 + t] = y;
  embh[(size_t)n * 128 + t] = f2bf(y);
}

// ---------------- Fused MLP heads (wave per row) ----------------
__global__ __launch_bounds__(256) void k_head_ret(const float* __restrict__ in,
    const float* __restrict__ W1, const float* __restrict__ b1,
    const float* __restrict__ W2, const float* __restrict__ b2,
    const float* __restrict__ W3, const float* __restrict__ b3,
    float* __restrict__ out) {
  __shared__ float sh[4][224];
  int wid = threadIdx.x >> 6, lane = threadIdx.x & 63;
  int row = blockIdx.x * 4 + wid;
  const float2* rp = reinterpret_cast<const float2*>(in + (size_t)row * 128);
  float2 f2 = rp[lane];
  sh[wid][2 * lane] = f2.x;
  sh[wid][2 * lane + 1] = f2.y;
  __syncthreads();
  float a = b1[lane];
#pragma unroll 8
  for (int k = 0; k < 128; ++k) a = fmaf(sh[wid][k], W1[k * 64 + lane], a);
  sh[wid][128 + lane] = fmaxf(a, 0.f);
  __syncthreads();
  if (lane < 32) {
    float a2 = b2[lane];
#pragma unroll 8
    for (int k = 0; k < 64; ++k) a2 = fmaf(sh[wid][128 + k], W2[k * 32 + lane], a2);
    sh[wid][192 + lane] = fmaxf(a2, 0.f);
  }
  __syncthreads();
  if (lane == 0) {
    float a3 = b3[0];
#pragma unroll
    for (int k = 0; k < 32; ++k) a3 = fmaf(sh[wid][192 + k], W3[k], a3);
    out[row] = tanhf(a3) * 0.1f;
  }
}

__global__ __launch_bounds__(256) void k_head_mov(const float* __restrict__ in,
    const float* __restrict__ W1, const float* __restrict__ b1,
    const float* __restrict__ W2, const float* __restrict__ b2,
    float* __restrict__ out) {
  __shared__ float sh[4][192];
  int wid = threadIdx.x >> 6, lane = threadIdx.x & 63;
  int row = blockIdx.x * 4 + wid;
  const float2* rp = reinterpret_cast<const float2*>(in + (size_t)row * 128);
  float2 f2 = rp[lane];
  sh[wid][2 * lane] = f2.x;
  sh[wid][2 * lane + 1] = f2.y;
  __syncthreads();
  float a = b1[lane];
#pragma unroll 8
  for (int k = 0; k < 128; ++k) a = fmaf(sh[wid][k], W1[k * 64 + lane], a);
  sh[wid][128 + lane] = fmaxf(a, 0.f);
  __syncthreads();
  if (lane < 2) {
    float a2 = b2[lane];
#pragma unroll 8
    for (int k = 0; k < 64; ++k) a2 = fmaf(sh[wid][128 + k], W2[k * 2 + lane], a2);
    out[(size_t)row * 2 + lane] = a2;
  }
}

__global__ __launch_bounds__(256) void k_head_rank(const float* __restrict__ in,
    const float* __restrict__ W1, const float* __restrict__ b1,
    const float* __restrict__ W2, const float* __restrict__ b2,
    float* __restrict__ out) {
  __shared__ float sh[4][192];
  int wid = threadIdx.x >> 6, lane = threadIdx.x & 63;
  int row = blockIdx.x * 4 + wid;
  const float2* rp = reinterpret_cast<const float2*>(in + (size_t)row * 128);
  float2 f2 = rp[lane];
  sh[wid][2 * lane] = f2.x;
  sh[wid][2 * lane + 1] = f2.y;
  __syncthreads();
  float a = b1[lane];
#pragma unroll 8
  for (int k = 0; k < 128; ++k) a = fmaf(sh[wid][k], W1[k * 64 + lane], a);
  sh[wid][128 + lane] = fmaxf(a, 0.f);
  __syncthreads();
  if (lane == 0) {
    float a2 = b2[0];
#pragma unroll 8
    for (int k = 0; k < 64; ++k) a2 = fmaf(sh[wid][128 + k], W2[k], a2);
    out[row] = 1.0f / (1.0f + expf(-a2));
  }
}

// ---------------- launch ----------------
extern "C" void kernel_launch(void* const* d_in, const int* in_sizes, int n_in,
                              void* d_out, int out_size, void* d_ws, size_t ws_size,
                              hipStream_t stream) {
  const float* x     = (const float*)d_in[0];
  const int*   ei    = (const int*)  d_in[1];
  const float* fn_g  = (const float*)d_in[2];
  const float* fn_b  = (const float*)d_in[3];
  const float* W_in  = (const float*)d_in[4];
  const float* b_in  = (const float*)d_in[5];
  const float* Wl1   = (const float*)d_in[6];
  const float* bl1   = (const float*)d_in[7];
  const float* Wr1   = (const float*)d_in[8];
  const float* br1   = (const float*)d_in[9];
  const float* att1  = (const float*)d_in[10];
  const float* bg1   = (const float*)d_in[11];
  const float* Wl2   = (const float*)d_in[12];
  const float* bl2   = (const float*)d_in[13];
  const float* Wr2   = (const float*)d_in[14];
  const float* br2   = (const float*)d_in[15];
  const float* att2  = (const float*)d_in[16];
  const float* bg2   = (const float*)d_in[17];
  const float* ln1_g = (const float*)d_in[18];
  const float* ln1_b = (const float*)d_in[19];
  const float* ln2_g = (const float*)d_in[20];
  const float* ln2_b = (const float*)d_in[21];
  const float* Wrf   = (const float*)d_in[22];
  const float* brf   = (const float*)d_in[23];
  const float* rf_g  = (const float*)d_in[24];
  const float* rf_b  = (const float*)d_in[25];
  const float* Wcf   = (const float*)d_in[26];
  const float* bcf   = (const float*)d_in[27];
  const float* cf_g  = (const float*)d_in[28];
  const float* cf_b  = (const float*)d_in[29];
  const float* Wkf   = (const float*)d_in[30];
  const float* bkf   = (const float*)d_in[31];
  const float* kf_g  = (const float*)d_in[32];
  const float* kf_b  = (const float*)d_in[33];
  const float* Wr1h  = (const float*)d_in[34];
  const float* br1h  = (const float*)d_in[35];
  const float* Wr2h  = (const float*)d_in[36];
  const float* br2h  = (const float*)d_in[37];
  const float* Wr3h  = (const float*)d_in[38];
  const float* br3h  = (const float*)d_in[39];
  const float* Wc1h  = (const float*)d_in[40];
  const float* bc1h  = (const float*)d_in[41];
  const float* Wc2h  = (const float*)d_in[42];
  const float* bc2h  = (const float*)d_in[43];
  const float* Wk1h  = (const float*)d_in[44];
  const float* bk1h  = (const float*)d_in[45];
  const float* Wk2h  = (const float*)d_in[46];
  const float* bk2h  = (const float*)d_in[47];

  const int M  = in_sizes[0] / 128;   // 20000
  const int E0 = in_sizes[1] / 2;     // 320000
  const int ET = E0 + M;              // 340000

  char* base = (char*)d_ws;
  size_t off = 0;
  auto carve = [&](size_t bytes) -> char* {
    off = (off + 255) & ~(size_t)255;
    char* p = base + off;
    off += bytes;
    return p;
  };
  const size_t B512 = (size_t)M * 512 * 2;  // bf16
  const size_t B128 = (size_t)M * 128 * 2;
  unsigned short* hnh  = (unsigned short*)carve(B128);
  unsigned short* h0h  = (unsigned short*)carve(B128);
  unsigned short* xl1h = (unsigned short*)carve(B512);
  unsigned short* xr1h = (unsigned short*)carve(B512);
  unsigned short* g1h  = (unsigned short*)carve(B512);
  unsigned short* xl2h = (unsigned short*)carve(B128);
  unsigned short* xr2h = (unsigned short*)carve(B128);
  unsigned short* embh = (unsigned short*)carve(B128);
  float* lg1 = (float*)carve((size_t)ET * 4 * sizeof(float));
  float* lg2 = (float*)carve((size_t)ET * sizeof(float));
  int* src_s = (int*)carve((size_t)ET * sizeof(int));
  int* dst_s = (int*)carve((size_t)ET * sizeof(int));
  int* cnt   = (int*)carve((size_t)2 * M * sizeof(int));
  int* cur   = cnt + M;
  int* offs  = (int*)carve((size_t)(M + 1) * sizeof(int));
  // packed weights (bf16, fragment order)
  unsigned short* Winp = (unsigned short*)carve(128 * 128 * 2);
  unsigned short* Wl1p = (unsigned short*)carve(128 * 512 * 2);
  unsigned short* Wr1p = (unsigned short*)carve(128 * 512 * 2);
  unsigned short* Wl2p = (unsigned short*)carve(512 * 128 * 2);
  unsigned short* Wr2p = (unsigned short*)carve(512 * 128 * 2);
  unsigned short* Wrfp = (unsigned short*)carve(128 * 128 * 2);
  unsigned short* Wcfp = (unsigned short*)carve(128 * 128 * 2);
  unsigned short* Wkfp = (unsigned short*)carve(128 * 128 * 2);
  // f32 feature buffers overlay the xl1h/xr1h region (dead after k_agg1)
  float* rf = (float*)xl1h;
  float* cf = (float*)((char*)xl1h + (size_t)M * 128 * 4);
  float* kf = (float*)xr1h;
  (void)ws_size; (void)n_in; (void)out_size;

  // CSR by dst
  hipMemsetAsync(cnt, 0, (size_t)2 * M * sizeof(int), stream);
  k_count<<<(ET + 255) / 256, 256, 0, stream>>>(ei, cnt, E0, ET);
  k_scan2<<<1, 1024, 0, stream>>>(cnt, offs, M);
  k_scatter<<<(ET + 255) / 256, 256, 0, stream>>>(ei, offs, cur, src_s, dst_s, E0, ET);

  // weight packing
  k_pack<<<(128 * 128 + 255) / 256, 256, 0, stream>>>(W_in, Winp, 128, 128);
  k_pack<<<(128 * 512 + 255) / 256, 256, 0, stream>>>(Wl1, Wl1p, 128, 512);
  k_pack<<<(128 * 512 + 255) / 256, 256, 0, stream>>>(Wr1, Wr1p, 128, 512);
  k_pack<<<(512 * 128 + 255) / 256, 256, 0, stream>>>(Wl2, Wl2p, 512, 128);
  k_pack<<<(512 * 128 + 255) / 256, 256, 0, stream>>>(Wr2, Wr2p, 512, 128);
  k_pack<<<(128 * 128 + 255) / 256, 256, 0, stream>>>(Wrf, Wrfp, 128, 128);
  k_pack<<<(128 * 128 + 255) / 256, 256, 0, stream>>>(Wcf, Wcfp, 128, 128);
  k_pack<<<(128 * 128 + 255) / 256, 256, 0, stream>>>(Wkf, Wkfp, 128, 128);

  // node pipeline (bf16 flow, f32 accum)
  k_ln<128, 0, true><<<M, 128, 0, stream>>>(x, hnh, fn_g, fn_b);
  k_mfma<128, 128, 1, false, true><<<M / 16, 256, 0, stream>>>(hnh, Winp, b_in, nullptr, h0h);
  k_mfma<128, 512, 0, false, true><<<M / 16, 256, 0, stream>>>(h0h, Wl1p, bl1, nullptr, xl1h);
  k_mfma<128, 512, 0, false, true><<<M / 16, 256, 0, stream>>>(h0h, Wr1p, br1, nullptr, xr1h);
  k_logits1<<<(ET + 3) / 4, 256, 0, stream>>>(src_s, dst_s, xl1h, xr1h, att1, lg1, ET);
  k_agg1<<<M, 256, 0, stream>>>(offs, src_s, lg1, (const unsigned*)xl1h, bg1,
                                ln1_g, ln1_b, (unsigned*)g1h);
  k_mfma<512, 128, 0, false, true><<<M / 16, 256, 0, stream>>>(g1h, Wl2p, bl2, nullptr, xl2h);
  k_mfma<512, 128, 0, false, true><<<M / 16, 256, 0, stream>>>(g1h, Wr2p, br2, nullptr, xr2h);
  k_logits2<<<(ET + 3) / 4, 256, 0, stream>>>(src_s, dst_s, xl2h, xr2h, att2, lg2, ET);

  float* out_ret  = (float*)d_out;
  float* out_mov  = out_ret + M;
  float* out_rank = out_ret + 3 * M;
  float* emb      = out_ret + 4 * M;
  k_agg2<<<M, 128, 0, stream>>>(offs, src_s, lg2, xl2h, bg2, ln2_g, ln2_b, emb, embh);

  // feature branches (MFMA f32 out, then LN+relu in place)
  k_mfma<128, 128, 0, true, false><<<M / 16, 256, 0, stream>>>(embh, Wrfp, brf, rf, nullptr);
  k_mfma<128, 128, 0, true, false><<<M / 16, 256, 0, stream>>>(embh, Wcfp, bcf, cf, nullptr);
  k_mfma<128, 128, 0, true, false><<<M / 16, 256, 0, stream>>>(embh, Wkfp, bkf, kf, nullptr);
  k_ln<128, 1, false><<<M, 128, 0, stream>>>(rf, rf, rf_g, rf_b);
  k_ln<128, 1, false><<<M, 128, 0, stream>>>(cf, cf, cf_g, cf_b);
  k_ln<128, 1, false><<<M, 128, 0, stream>>>(kf, kf, kf_g, kf_b);

  // heads
  k_head_ret<<<M / 4, 256, 0, stream>>>(rf, Wr1h, br1h, Wr2h, br2h, Wr3h, br3h, out_ret);
  k_head_mov<<<M / 4, 256, 0, stream>>>(cf, Wc1h, bc1h, Wc2h, bc2h, out_mov);
  k_head_rank<<<M / 4, 256, 0, stream>>>(kf, Wk1h, bk1h, Wk2h, bk2h, out_rank);
}

// Round 4
// 414.202 us; speedup vs baseline: 1.9767x; 1.1926x over previous
//
#include <hip/hip_runtime.h>
#include <cmath>

#define DEV __device__ __forceinline__

typedef __attribute__((ext_vector_type(8))) unsigned short ushort8v;
typedef __attribute__((ext_vector_type(8))) short short8v;
typedef __attribute__((ext_vector_type(4))) float f32x4;

DEV float lrelu(float v) { return v > 0.f ? v : 0.2f * v; }
DEV float elu(float v) { return v > 0.f ? v : expm1f(v); }
DEV float bf2f(unsigned short u) { return __uint_as_float((unsigned)u << 16); }
DEV float plo(unsigned u) { return __uint_as_float(u << 16); }
DEV float phi(unsigned u) { return __uint_as_float(u & 0xffff0000u); }
DEV unsigned short f2bf(float f) {
  unsigned u = __float_as_uint(f);
  unsigned r = (u + 0x7fffu + ((u >> 16) & 1u)) >> 16;
  return (unsigned short)r;
}
DEV unsigned packbf(float a, float b) {
  return (unsigned)f2bf(a) | ((unsigned)f2bf(b) << 16);
}

// ---------------- CSR build ----------------
__global__ void k_count(const int* __restrict__ ei, int* __restrict__ counts,
                        int E0, int ET) {
  int e = blockIdx.x * 256 + threadIdx.x;
  if (e >= ET) return;
  int dst = (e < E0) ? ei[E0 + e] : (e - E0);
  atomicAdd(&counts[dst], 1);
}

__global__ __launch_bounds__(1024) void k_scan2(const int* __restrict__ counts,
                                                int* __restrict__ offs, int n) {
  int t = threadIdx.x;
  int ch = (n + 1023) >> 10;
  int beg = t * ch, end = min(beg + ch, n);
  int loc = 0;
  for (int i = beg; i < end; ++i) loc += counts[i];
  int lane = t & 63, w = t >> 6;
  int v = loc;
#pragma unroll
  for (int m = 1; m < 64; m <<= 1) {
    int u = __shfl_up(v, m);
    if (lane >= m) v += u;
  }
  __shared__ int wsum[16], wpre[16];
  if (lane == 63) wsum[w] = v;
  __syncthreads();
  if (t < 16) {
    int p = 0;
    for (int i = 0; i < t; ++i) p += wsum[i];
    wpre[t] = p;
  }
  __syncthreads();
  int run = wpre[w] + v - loc;
  for (int i = beg; i < end; ++i) { offs[i] = run; run += counts[i]; }
  if (beg < n && end == n) offs[n] = run;
}

__global__ void k_scatter(const int* __restrict__ ei, const int* __restrict__ offs,
                          int* __restrict__ cursor, int* __restrict__ src_s,
                          int E0, int ET) {
  int e = blockIdx.x * 256 + threadIdx.x;
  if (e >= ET) return;
  int src, dst;
  if (e < E0) { src = ei[e]; dst = ei[E0 + e]; }
  else        { src = e - E0; dst = e - E0; }
  int pos = offs[dst] + atomicAdd(&cursor[dst], 1);
  src_s[pos] = src;
}

// ---------------- Weight pack into MFMA B-fragment order ----------------
DEV void pack_one(const float* __restrict__ W, unsigned short* __restrict__ Wp,
                  int K, int N, int idx) {
  if (idx >= K * N) return;
  int j = idx & 7, l = (idx >> 3) & 63, r = idx >> 9;
  int KB = K / 32;
  int tile = r / KB, kb = r - tile * KB;
  int k = kb * 32 + (l >> 4) * 8 + j;
  int col = tile * 16 + (l & 15);
  Wp[idx] = f2bf(W[(size_t)k * N + col]);
}

__global__ void k_pack_all(const float* w0, const float* w1, const float* w2,
                           const float* w3, const float* w4, const float* w5,
                           const float* w6, const float* w7,
                           unsigned short* p0, unsigned short* p1, unsigned short* p2,
                           unsigned short* p3, unsigned short* p4, unsigned short* p5,
                           unsigned short* p6, unsigned short* p7) {
  int idx = blockIdx.x * 256 + threadIdx.x;
  pack_one(w0, p0, 128, 128, idx);
  pack_one(w1, p1, 128, 512, idx);
  pack_one(w2, p2, 128, 512, idx);
  pack_one(w3, p3, 512, 128, idx);
  pack_one(w4, p4, 512, 128, idx);
  pack_one(w5, p5, 128, 128, idx);
  pack_one(w6, p6, 128, 128, idx);
  pack_one(w7, p7, 128, 128, idx);
}

// ---------------- MFMA GEMM: C[M,N] = act(A[M,K](bf16) @ W + bias) ----------------
template<int K, int N, int ACT, bool OF32, bool OB16>
__global__ __launch_bounds__(256) void k_mfma(const unsigned short* __restrict__ A,
                                              const unsigned short* __restrict__ Wp,
                                              const float* __restrict__ bias,
                                              float* __restrict__ Cf,
                                              unsigned short* __restrict__ Cb) {
  constexpr int KB = K / 32;
  constexpr int TPW = N / 64;
  __shared__ short As[KB * 64 * 8];
  int row0 = blockIdx.x * 16;
  int t = threadIdx.x, lane = t & 63, w = t >> 6;
  for (int idx = t; idx < KB * 64; idx += 256) {
    int kb = idx >> 6, l = idx & 63;
    const short8v* sp = reinterpret_cast<const short8v*>(
        A + (size_t)(row0 + (l & 15)) * K + kb * 32 + (l >> 4) * 8);
    reinterpret_cast<short8v*>(As)[idx] = *sp;
  }
  __syncthreads();
  f32x4 acc[TPW];
#pragma unroll
  for (int j = 0; j < TPW; ++j) acc[j] = f32x4{0.f, 0.f, 0.f, 0.f};
  const short8v* Bp = reinterpret_cast<const short8v*>(Wp);
  for (int kb = 0; kb < KB; ++kb) {
    short8v a = reinterpret_cast<const short8v*>(As)[kb * 64 + lane];
#pragma unroll
    for (int j = 0; j < TPW; ++j) {
      int tile = w * TPW + j;
      short8v b = Bp[(tile * KB + kb) * 64 + lane];
      acc[j] = __builtin_amdgcn_mfma_f32_16x16x32_bf16(a, b, acc[j], 0, 0, 0);
    }
  }
#pragma unroll
  for (int j = 0; j < TPW; ++j) {
    int col = (w * TPW + j) * 16 + (lane & 15);
    float bs = bias[col];
#pragma unroll
    for (int r = 0; r < 4; ++r) {
      int row = row0 + (lane >> 4) * 4 + r;
      float v = acc[j][r] + bs;
      if (ACT == 1) v = fmaxf(v, 0.f);
      if (OF32) Cf[(size_t)row * N + col] = v;
      if (OB16) Cb[(size_t)row * N + col] = f2bf(v);
    }
  }
}

// ---------------- LayerNorm (x -> bf16) ----------------
template<int C, int ACT, bool OUT16>
__global__ void k_ln(const float* in, void* out, const float* g, const float* b) {
  constexpr int T = (C < 256) ? C : 256;
  constexpr int EPT = C / T;
  int row = blockIdx.x, t = threadIdx.x;
  const float* ip = in + (size_t)row * C;
  float v[EPT];
  float s = 0.f, s2 = 0.f;
#pragma unroll
  for (int e = 0; e < EPT; ++e) { float xv = ip[t + e * T]; v[e] = xv; s += xv; s2 += xv * xv; }
#pragma unroll
  for (int m = 1; m <= 32; m <<= 1) { s += __shfl_xor(s, m); s2 += __shfl_xor(s2, m); }
  __shared__ float w1s[2], w2s[2];
  if (T > 64) {
    if ((t & 63) == 0) { w1s[t >> 6] = s; w2s[t >> 6] = s2; }
    __syncthreads();
    s = w1s[0] + w1s[1];
    s2 = w2s[0] + w2s[1];
  }
  float mu = s * (1.0f / C);
  float var = s2 * (1.0f / C) - mu * mu;
  float rs = rsqrtf(var + 1e-5f);
#pragma unroll
  for (int e = 0; e < EPT; ++e) {
    int c = t + e * T;
    float y = (v[e] - mu) * rs * g[c] + b[c];
    if (ACT == 1) y = fmaxf(y, 0.f);
    if (ACT == 2) y = elu(y);
    if (OUT16) ((unsigned short*)out)[(size_t)row * C + c] = f2bf(y);
    else       ((float*)out)[(size_t)row * C + c] = y;
  }
}

// ---------------- Fused GATv2 layer 1: logits + online softmax + agg + LN + elu ----------------
// Block per dst node; wave w owns head w (channels w*128..w*128+127); thread t owns ch 2t,2t+1.
__global__ __launch_bounds__(256) void k_gat1(const int* __restrict__ offs,
                                              const int* __restrict__ src_s,
                                              const unsigned* __restrict__ xlh,  // [M][256] pairs
                                              const unsigned* __restrict__ xrh,  // [M][256] pairs
                                              const float* __restrict__ att,     // [512]
                                              const float* __restrict__ bg,
                                              const float* __restrict__ lg,
                                              const float* __restrict__ lb,
                                              unsigned* __restrict__ outh) {     // [M][256] pairs
  int n = blockIdx.x;
  int st = offs[n], en = offs[n + 1];
  int t = threadIdx.x;
  unsigned ur = xrh[(size_t)n * 256 + t];
  float xr0 = plo(ur), xr1 = phi(ur);
  float at0 = att[2 * t], at1 = att[2 * t + 1];
  float m = -3.0e38f, s = 0.f, acc0 = 0.f, acc1 = 0.f;
  // software-pipelined gather
  unsigned u = xlh[(size_t)src_s[st] * 256 + t];
  for (int i = st; i < en; ++i) {
    unsigned ucur = u;
    if (i + 1 < en) u = xlh[(size_t)src_s[i + 1] * 256 + t];
    float x0 = plo(ucur), x1 = phi(ucur);
    float p = at0 * lrelu(x0 + xr0) + at1 * lrelu(x1 + xr1);
#pragma unroll
    for (int mm = 1; mm <= 32; mm <<= 1) p += __shfl_xor(p, mm);
    float mn = fmaxf(m, p);
    float al = __expf(m - mn);
    float we = __expf(p - mn);
    s = s * al + we;
    acc0 = acc0 * al + we * x0;
    acc1 = acc1 * al + we * x1;
    m = mn;
  }
  float inv = 1.0f / (s + 1e-16f);
  float v0 = acc0 * inv + bg[2 * t];
  float v1 = acc1 * inv + bg[2 * t + 1];
  // fused LN over 512 channels
  float rs = v0 + v1, rs2 = v0 * v0 + v1 * v1;
#pragma unroll
  for (int mm = 1; mm <= 32; mm <<= 1) { rs += __shfl_xor(rs, mm); rs2 += __shfl_xor(rs2, mm); }
  __shared__ float r1[4], r2[4];
  if ((t & 63) == 0) { r1[t >> 6] = rs; r2[t >> 6] = rs2; }
  __syncthreads();
  rs = r1[0] + r1[1] + r1[2] + r1[3];
  rs2 = r2[0] + r2[1] + r2[2] + r2[3];
  float mu = rs * (1.0f / 512.0f);
  float var = rs2 * (1.0f / 512.0f) - mu * mu;
  float rsd = rsqrtf(var + 1e-5f);
  float y0 = elu((v0 - mu) * rsd * lg[2 * t] + lb[2 * t]);
  float y1 = elu((v1 - mu) * rsd * lg[2 * t + 1] + lb[2 * t + 1]);
  outh[(size_t)n * 256 + t] = packbf(y0, y1);
}

// ---------------- Fused GATv2 layer 2: wave per node; logits + online softmax + agg + LN + elu ----------------
__global__ __launch_bounds__(256) void k_gat2(const int* __restrict__ offs,
                                              const int* __restrict__ src_s,
                                              const unsigned* __restrict__ xlh,  // [M][64] pairs
                                              const unsigned* __restrict__ xrh,
                                              const float* __restrict__ att,     // [128]
                                              const float* __restrict__ bg,
                                              const float* __restrict__ lg,
                                              const float* __restrict__ lb,
                                              float* __restrict__ emb,
                                              unsigned short* __restrict__ embh,
                                              int M) {
  int w = threadIdx.x >> 6, lane = threadIdx.x & 63;
  int n = blockIdx.x * 4 + w;
  if (n >= M) return;
  int st = offs[n], en = offs[n + 1];
  unsigned ur = xrh[(size_t)n * 64 + lane];
  float xr0 = plo(ur), xr1 = phi(ur);
  float at0 = att[2 * lane], at1 = att[2 * lane + 1];
  float m = -3.0e38f, s = 0.f, acc0 = 0.f, acc1 = 0.f;
  unsigned u = xlh[(size_t)src_s[st] * 64 + lane];
  for (int i = st; i < en; ++i) {
    unsigned ucur = u;
    if (i + 1 < en) u = xlh[(size_t)src_s[i + 1] * 64 + lane];
    float x0 = plo(ucur), x1 = phi(ucur);
    float p = at0 * lrelu(x0 + xr0) + at1 * lrelu(x1 + xr1);
#pragma unroll
    for (int mm = 1; mm <= 32; mm <<= 1) p += __shfl_xor(p, mm);
    float mn = fmaxf(m, p);
    float al = __expf(m - mn);
    float we = __expf(p - mn);
    s = s * al + we;
    acc0 = acc0 * al + we * x0;
    acc1 = acc1 * al + we * x1;
    m = mn;
  }
  float inv = 1.0f / (s + 1e-16f);
  float v0 = acc0 * inv + bg[2 * lane];
  float v1 = acc1 * inv + bg[2 * lane + 1];
  float rs = v0 + v1, rs2 = v0 * v0 + v1 * v1;
#pragma unroll
  for (int mm = 1; mm <= 32; mm <<= 1) { rs += __shfl_xor(rs, mm); rs2 += __shfl_xor(rs2, mm); }
  float mu = rs * (1.0f / 128.0f);
  float var = rs2 * (1.0f / 128.0f) - mu * mu;
  float rsd = rsqrtf(var + 1e-5f);
  float y0 = elu((v0 - mu) * rsd * lg[2 * lane] + lb[2 * lane]);
  float y1 = elu((v1 - mu) * rsd * lg[2 * lane + 1] + lb[2 * lane + 1]);
  *reinterpret_cast<float2*>(emb + (size_t)n * 128 + 2 * lane) = float2{y0, y1};
  reinterpret_cast<unsigned*>(embh)[(size_t)n * 64 + lane] = packbf(y0, y1);
}

// ---------------- Fused branch GEMM (N=384) + per-segment LN + relu ----------------
__global__ __launch_bounds__(256) void k_branch(const unsigned short* __restrict__ A,
    const unsigned short* __restrict__ Wp,
    const float* __restrict__ b0, const float* __restrict__ b1s, const float* __restrict__ b2s,
    const float* __restrict__ g0, const float* __restrict__ gb0,
    const float* __restrict__ g1, const float* __restrict__ gb1,
    const float* __restrict__ g2, const float* __restrict__ gb2,
    float* __restrict__ ff) {
  constexpr int KB = 4, TPW = 6;
  __shared__ short As[KB * 64 * 8];
  __shared__ float Cs[16 * 384];
  int row0 = blockIdx.x * 16;
  int t = threadIdx.x, lane = t & 63, w = t >> 6;
  for (int idx = t; idx < KB * 64; idx += 256) {
    int kb = idx >> 6, l = idx & 63;
    const short8v* sp = reinterpret_cast<const short8v*>(
        A + (size_t)(row0 + (l & 15)) * 128 + kb * 32 + (l >> 4) * 8);
    reinterpret_cast<short8v*>(As)[idx] = *sp;
  }
  __syncthreads();
  f32x4 acc[TPW];
#pragma unroll
  for (int j = 0; j < TPW; ++j) acc[j] = f32x4{0.f, 0.f, 0.f, 0.f};
  const short8v* Bp = reinterpret_cast<const short8v*>(Wp);
  for (int kb = 0; kb < KB; ++kb) {
    short8v a = reinterpret_cast<const short8v*>(As)[kb * 64 + lane];
#pragma unroll
    for (int j = 0; j < TPW; ++j) {
      int tile = w * TPW + j;
      short8v b = Bp[(tile * KB + kb) * 64 + lane];
      acc[j] = __builtin_amdgcn_mfma_f32_16x16x32_bf16(a, b, acc[j], 0, 0, 0);
    }
  }
#pragma unroll
  for (int j = 0; j < TPW; ++j) {
    int col = (w * TPW + j) * 16 + (lane & 15);
    int seg = col >> 7, cl = col & 127;
    const float* bp = (seg == 0) ? b0 : (seg == 1) ? b1s : b2s;
    float bs = bp[cl];
#pragma unroll
    for (int r = 0; r < 4; ++r)
      Cs[((lane >> 4) * 4 + r) * 384 + col] = acc[j][r] + bs;
  }
  __syncthreads();
  int row = t >> 4, l16 = t & 15;
#pragma unroll
  for (int seg = 0; seg < 3; ++seg) {
    float v[8];
    float s = 0.f, s2 = 0.f;
    int base = row * 384 + seg * 128 + l16 * 8;
#pragma unroll
    for (int k = 0; k < 8; ++k) { v[k] = Cs[base + k]; s += v[k]; s2 += v[k] * v[k]; }
#pragma unroll
    for (int mm = 1; mm <= 8; mm <<= 1) { s += __shfl_xor(s, mm); s2 += __shfl_xor(s2, mm); }
    float mu = s * (1.0f / 128.0f);
    float var = s2 * (1.0f / 128.0f) - mu * mu;
    float rsd = rsqrtf(var + 1e-5f);
    const float* gp = (seg == 0) ? g0 : (seg == 1) ? g1 : g2;
    const float* bp = (seg == 0) ? gb0 : (seg == 1) ? gb1 : gb2;
    float* op = ff + (size_t)(row0 + row) * 384 + seg * 128 + l16 * 8;
#pragma unroll
    for (int k = 0; k < 8; ++k) {
      int c = l16 * 8 + k;
      op[k] = fmaxf((v[k] - mu) * rsd * gp[c] + bp[c], 0.f);
    }
  }
}

// ---------------- Fused MLP heads (wave per row) ----------------
__global__ __launch_bounds__(256) void k_head_ret(const float* __restrict__ in, int ldi,
    const float* __restrict__ W1, const float* __restrict__ b1,
    const float* __restrict__ W2, const float* __restrict__ b2,
    const float* __restrict__ W3, const float* __restrict__ b3,
    float* __restrict__ out) {
  __shared__ float sh[4][224];
  int wid = threadIdx.x >> 6, lane = threadIdx.x & 63;
  int row = blockIdx.x * 4 + wid;
  const float2* rp = reinterpret_cast<const float2*>(in + (size_t)row * ldi);
  float2 f2 = rp[lane];
  sh[wid][2 * lane] = f2.x;
  sh[wid][2 * lane + 1] = f2.y;
  __syncthreads();
  float a = b1[lane];
#pragma unroll 8
  for (int k = 0; k < 128; ++k) a = fmaf(sh[wid][k], W1[k * 64 + lane], a);
  sh[wid][128 + lane] = fmaxf(a, 0.f);
  __syncthreads();
  if (lane < 32) {
    float a2 = b2[lane];
#pragma unroll 8
    for (int k = 0; k < 64; ++k) a2 = fmaf(sh[wid][128 + k], W2[k * 32 + lane], a2);
    sh[wid][192 + lane] = fmaxf(a2, 0.f);
  }
  __syncthreads();
  if (lane == 0) {
    float a3 = b3[0];
#pragma unroll
    for (int k = 0; k < 32; ++k) a3 = fmaf(sh[wid][192 + k], W3[k], a3);
    out[row] = tanhf(a3) * 0.1f;
  }
}

__global__ __launch_bounds__(256) void k_head_mov(const float* __restrict__ in, int ldi,
    const float* __restrict__ W1, const float* __restrict__ b1,
    const float* __restrict__ W2, const float* __restrict__ b2,
    float* __restrict__ out) {
  __shared__ float sh[4][192];
  int wid = threadIdx.x >> 6, lane = threadIdx.x & 63;
  int row = blockIdx.x * 4 + wid;
  const float2* rp = reinterpret_cast<const float2*>(in + (size_t)row * ldi);
  float2 f2 = rp[lane];
  sh[wid][2 * lane] = f2.x;
  sh[wid][2 * lane + 1] = f2.y;
  __syncthreads();
  float a = b1[lane];
#pragma unroll 8
  for (int k = 0; k < 128; ++k) a = fmaf(sh[wid][k], W1[k * 64 + lane], a);
  sh[wid][128 + lane] = fmaxf(a, 0.f);
  __syncthreads();
  if (lane < 2) {
    float a2 = b2[lane];
#pragma unroll 8
    for (int k = 0; k < 64; ++k) a2 = fmaf(sh[wid][128 + k], W2[k * 2 + lane], a2);
    out[(size_t)row * 2 + lane] = a2;
  }
}

__global__ __launch_bounds__(256) void k_head_rank(const float* __restrict__ in, int ldi,
    const float* __restrict__ W1, const float* __restrict__ b1,
    const float* __restrict__ W2, const float* __restrict__ b2,
    float* __restrict__ out) {
  __shared__ float sh[4][192];
  int wid = threadIdx.x >> 6, lane = threadIdx.x & 63;
  int row = blockIdx.x * 4 + wid;
  const float2* rp = reinterpret_cast<const float2*>(in + (size_t)row * ldi);
  float2 f2 = rp[lane];
  sh[wid][2 * lane] = f2.x;
  sh[wid][2 * lane + 1] = f2.y;
  __syncthreads();
  float a = b1[lane];
#pragma unroll 8
  for (int k = 0; k < 128; ++k) a = fmaf(sh[wid][k], W1[k * 64 + lane], a);
  sh[wid][128 + lane] = fmaxf(a, 0.f);
  __syncthreads();
  if (lane == 0) {
    float a2 = b2[0];
#pragma unroll 8
    for (int k = 0; k < 64; ++k) a2 = fmaf(sh[wid][128 + k], W2[k], a2);
    out[row] = 1.0f / (1.0f + expf(-a2));
  }
}

// ---------------- launch ----------------
extern "C" void kernel_launch(void* const* d_in, const int* in_sizes, int n_in,
                              void* d_out, int out_size, void* d_ws, size_t ws_size,
                              hipStream_t stream) {
  const float* x     = (const float*)d_in[0];
  const int*   ei    = (const int*)  d_in[1];
  const float* fn_g  = (const float*)d_in[2];
  const float* fn_b  = (const float*)d_in[3];
  const float* W_in  = (const float*)d_in[4];
  const float* b_in  = (const float*)d_in[5];
  const float* Wl1   = (const float*)d_in[6];
  const float* bl1   = (const float*)d_in[7];
  const float* Wr1   = (const float*)d_in[8];
  const float* br1   = (const float*)d_in[9];
  const float* att1  = (const float*)d_in[10];
  const float* bg1   = (const float*)d_in[11];
  const float* Wl2   = (const float*)d_in[12];
  const float* bl2   = (const float*)d_in[13];
  const float* Wr2   = (const float*)d_in[14];
  const float* br2   = (const float*)d_in[15];
  const float* att2  = (const float*)d_in[16];
  const float* bg2   = (const float*)d_in[17];
  const float* ln1_g = (const float*)d_in[18];
  const float* ln1_b = (const float*)d_in[19];
  const float* ln2_g = (const float*)d_in[20];
  const float* ln2_b = (const float*)d_in[21];
  const float* Wrf   = (const float*)d_in[22];
  const float* brf   = (const float*)d_in[23];
  const float* rf_g  = (const float*)d_in[24];
  const float* rf_b  = (const float*)d_in[25];
  const float* Wcf   = (const float*)d_in[26];
  const float* bcf   = (const float*)d_in[27];
  const float* cf_g  = (const float*)d_in[28];
  const float* cf_b  = (const float*)d_in[29];
  const float* Wkf   = (const float*)d_in[30];
  const float* bkf   = (const float*)d_in[31];
  const float* kf_g  = (const float*)d_in[32];
  const float* kf_b  = (const float*)d_in[33];
  const float* Wr1h  = (const float*)d_in[34];
  const float* br1h  = (const float*)d_in[35];
  const float* Wr2h  = (const float*)d_in[36];
  const float* br2h  = (const float*)d_in[37];
  const float* Wr3h  = (const float*)d_in[38];
  const float* br3h  = (const float*)d_in[39];
  const float* Wc1h  = (const float*)d_in[40];
  const float* bc1h  = (const float*)d_in[41];
  const float* Wc2h  = (const float*)d_in[42];
  const float* bc2h  = (const float*)d_in[43];
  const float* Wk1h  = (const float*)d_in[44];
  const float* bk1h  = (const float*)d_in[45];
  const float* Wk2h  = (const float*)d_in[46];
  const float* bk2h  = (const float*)d_in[47];

  const int M  = in_sizes[0] / 128;   // 20000
  const int E0 = in_sizes[1] / 2;     // 320000
  const int ET = E0 + M;              // 340000

  char* base = (char*)d_ws;
  size_t off = 0;
  auto carve = [&](size_t bytes) -> char* {
    off = (off + 255) & ~(size_t)255;
    char* p = base + off;
    off += bytes;
    return p;
  };
  const size_t B512 = (size_t)M * 512 * 2;  // bf16
  const size_t B128 = (size_t)M * 128 * 2;
  unsigned short* hnh  = (unsigned short*)carve(B128);
  unsigned short* h0h  = (unsigned short*)carve(B128);
  unsigned short* xl1h = (unsigned short*)carve(B512);
  unsigned short* xr1h = (unsigned short*)carve(B512);
  unsigned short* g1h  = (unsigned short*)carve(B512);
  unsigned short* xl2h = (unsigned short*)carve(B128);
  unsigned short* xr2h = (unsigned short*)carve(B128);
  unsigned short* embh = (unsigned short*)carve(B128);
  int* src_s = (int*)carve((size_t)ET * sizeof(int));
  int* cnt   = (int*)carve((size_t)2 * M * sizeof(int));
  int* cur   = cnt + M;
  int* offs  = (int*)carve((size_t)(M + 1) * sizeof(int));
  unsigned short* Winp = (unsigned short*)carve(128 * 128 * 2);
  unsigned short* Wl1p = (unsigned short*)carve(128 * 512 * 2);
  unsigned short* Wr1p = (unsigned short*)carve(128 * 512 * 2);
  unsigned short* Wl2p = (unsigned short*)carve(512 * 128 * 2);
  unsigned short* Wr2p = (unsigned short*)carve(512 * 128 * 2);
  unsigned short* Wtp  = (unsigned short*)carve(3 * 128 * 128 * 2);
  // ff [M][384] f32 overlays xl1h/xr1h (dead after k_gat1)
  float* ff = (float*)xl1h;
  (void)ws_size; (void)n_in; (void)out_size;

  // CSR by dst
  hipMemsetAsync(cnt, 0, (size_t)2 * M * sizeof(int), stream);
  k_count<<<(ET + 255) / 256, 256, 0, stream>>>(ei, cnt, E0, ET);
  k_scan2<<<1, 1024, 0, stream>>>(cnt, offs, M);
  k_scatter<<<(ET + 255) / 256, 256, 0, stream>>>(ei, offs, cur, src_s, E0, ET);

  // weight packing (one launch)
  k_pack_all<<<256, 256, 0, stream>>>(W_in, Wl1, Wr1, Wl2, Wr2, Wrf, Wcf, Wkf,
                                      Winp, Wl1p, Wr1p, Wl2p, Wr2p,
                                      Wtp, Wtp + 16384, Wtp + 32768);

  // node pipeline (bf16 flow, f32 accum)
  k_ln<128, 0, true><<<M, 128, 0, stream>>>(x, hnh, fn_g, fn_b);
  k_mfma<128, 128, 1, false, true><<<M / 16, 256, 0, stream>>>(hnh, Winp, b_in, nullptr, h0h);
  k_mfma<128, 512, 0, false, true><<<M / 16, 256, 0, stream>>>(h0h, Wl1p, bl1, nullptr, xl1h);
  k_mfma<128, 512, 0, false, true><<<M / 16, 256, 0, stream>>>(h0h, Wr1p, br1, nullptr, xr1h);
  k_gat1<<<M, 256, 0, stream>>>(offs, src_s, (const unsigned*)xl1h, (const unsigned*)xr1h,
                                att1, bg1, ln1_g, ln1_b, (unsigned*)g1h);
  k_mfma<512, 128, 0, false, true><<<M / 16, 256, 0, stream>>>(g1h, Wl2p, bl2, nullptr, xl2h);
  k_mfma<512, 128, 0, false, true><<<M / 16, 256, 0, stream>>>(g1h, Wr2p, br2, nullptr, xr2h);

  float* out_ret  = (float*)d_out;
  float* out_mov  = out_ret + M;
  float* out_rank = out_ret + 3 * M;
  float* emb      = out_ret + 4 * M;
  k_gat2<<<(M + 3) / 4, 256, 0, stream>>>(offs, src_s, (const unsigned*)xl2h,
                                          (const unsigned*)xr2h, att2, bg2,
                                          ln2_g, ln2_b, emb, embh, M);

  // fused feature branches (GEMM N=384 + LN + relu)
  k_branch<<<M / 16, 256, 0, stream>>>(embh, Wtp, brf, bcf, bkf,
                                       rf_g, rf_b, cf_g, cf_b, kf_g, kf_b, ff);

  // heads (read ff with stride 384, offsets 0/128/256)
  k_head_ret<<<M / 4, 256, 0, stream>>>(ff, 384, Wr1h, br1h, Wr2h, br2h, Wr3h, br3h, out_ret);
  k_head_mov<<<M / 4, 256, 0, stream>>>(ff + 128, 384, Wc1h, bc1h, Wc2h, bc2h, out_mov);
  k_head_rank<<<M / 4, 256, 0, stream>>>(ff + 256, 384, Wk1h, bk1h, Wk2h, bk2h, out_rank);
}

// Round 5
// 367.015 us; speedup vs baseline: 2.2308x; 1.1286x over previous
//
#include <hip/hip_runtime.h>
#include <cmath>

#define DEV __device__ __forceinline__

typedef __attribute__((ext_vector_type(8))) unsigned short ushort8v;
typedef __attribute__((ext_vector_type(8))) short short8v;
typedef __attribute__((ext_vector_type(4))) float f32x4;

DEV float lrelu(float v) { return v > 0.f ? v : 0.2f * v; }
DEV float elu(float v) { return v > 0.f ? v : expm1f(v); }
DEV float bf2f(unsigned short u) { return __uint_as_float((unsigned)u << 16); }
DEV float plo(unsigned u) { return __uint_as_float(u << 16); }
DEV float phi(unsigned u) { return __uint_as_float(u & 0xffff0000u); }
DEV unsigned short f2bf(float f) {
  unsigned u = __float_as_uint(f);
  unsigned r = (u + 0x7fffu + ((u >> 16) & 1u)) >> 16;
  return (unsigned short)r;
}
DEV unsigned packbf(float a, float b) {
  return (unsigned)f2bf(a) | ((unsigned)f2bf(b) << 16);
}

// ---------------- CSR build ----------------
__global__ void k_count(const int* __restrict__ ei, int* __restrict__ counts,
                        int E0, int ET) {
  int e = blockIdx.x * 256 + threadIdx.x;
  if (e >= ET) return;
  int dst = (e < E0) ? ei[E0 + e] : (e - E0);
  atomicAdd(&counts[dst], 1);
}

__global__ __launch_bounds__(1024) void k_scan2(const int* __restrict__ counts,
                                                int* __restrict__ offs, int n) {
  int t = threadIdx.x;
  int ch = (n + 1023) >> 10;
  int beg = t * ch, end = min(beg + ch, n);
  int loc = 0;
  for (int i = beg; i < end; ++i) loc += counts[i];
  int lane = t & 63, w = t >> 6;
  int v = loc;
#pragma unroll
  for (int m = 1; m < 64; m <<= 1) {
    int u = __shfl_up(v, m);
    if (lane >= m) v += u;
  }
  __shared__ int wsum[16], wpre[16];
  if (lane == 63) wsum[w] = v;
  __syncthreads();
  if (t < 16) {
    int p = 0;
    for (int i = 0; i < t; ++i) p += wsum[i];
    wpre[t] = p;
  }
  __syncthreads();
  int run = wpre[w] + v - loc;
  for (int i = beg; i < end; ++i) { offs[i] = run; run += counts[i]; }
  if (beg < n && end == n) offs[n] = run;
}

__global__ void k_scatter(const int* __restrict__ ei, const int* __restrict__ offs,
                          int* __restrict__ cursor, int* __restrict__ src_s,
                          int E0, int ET) {
  int e = blockIdx.x * 256 + threadIdx.x;
  if (e >= ET) return;
  int src, dst;
  if (e < E0) { src = ei[e]; dst = ei[E0 + e]; }
  else        { src = e - E0; dst = e - E0; }
  int pos = offs[dst] + atomicAdd(&cursor[dst], 1);
  src_s[pos] = src;
}

// ---------------- Weight pack into MFMA B-fragment order ----------------
DEV void pack_one(const float* __restrict__ W, unsigned short* __restrict__ Wp,
                  int K, int N, int idx) {
  if (idx >= K * N) return;
  int j = idx & 7, l = (idx >> 3) & 63, r = idx >> 9;
  int KB = K / 32;
  int tile = r / KB, kb = r - tile * KB;
  int k = kb * 32 + (l >> 4) * 8 + j;
  int col = tile * 16 + (l & 15);
  Wp[idx] = f2bf(W[(size_t)k * N + col]);
}

__global__ void k_pack_all(const float* w0, const float* w1, const float* w2,
                           const float* w3, const float* w4, const float* w5,
                           const float* w6, const float* w7,
                           unsigned short* p0, unsigned short* p1, unsigned short* p2,
                           unsigned short* p3, unsigned short* p4, unsigned short* p5,
                           unsigned short* p6, unsigned short* p7) {
  int idx = blockIdx.x * 256 + threadIdx.x;
  pack_one(w0, p0, 128, 128, idx);
  pack_one(w1, p1, 128, 512, idx);
  pack_one(w2, p2, 128, 512, idx);
  pack_one(w3, p3, 512, 128, idx);
  pack_one(w4, p4, 512, 128, idx);
  pack_one(w5, p5, 128, 128, idx);
  pack_one(w6, p6, 128, 128, idx);
  pack_one(w7, p7, 128, 128, idx);
}

// ---------------- MFMA GEMM: C[M,N] = act(A[M,K](bf16) @ W + bias), RT row-tiles ----------------
template<int K, int N, int RT, int ACT, bool OF32, bool OB16>
__global__ __launch_bounds__(256) void k_mfma(const unsigned short* __restrict__ A,
                                              const unsigned short* __restrict__ Wp,
                                              const float* __restrict__ bias,
                                              float* __restrict__ Cf,
                                              unsigned short* __restrict__ Cb) {
  constexpr int KB = K / 32;
  constexpr int TPW = N / 64;
  __shared__ short As[RT * KB * 64 * 8];
  int row0 = blockIdx.x * (16 * RT);
  int t = threadIdx.x, lane = t & 63, w = t >> 6;
  for (int idx = t; idx < RT * KB * 64; idx += 256) {
    int r = idx / (KB * 64), rem = idx - r * (KB * 64);
    int kb = rem >> 6, l = rem & 63;
    const short8v* sp = reinterpret_cast<const short8v*>(
        A + (size_t)(row0 + r * 16 + (l & 15)) * K + kb * 32 + (l >> 4) * 8);
    reinterpret_cast<short8v*>(As)[idx] = *sp;
  }
  __syncthreads();
  f32x4 acc[RT][TPW];
#pragma unroll
  for (int r = 0; r < RT; ++r)
#pragma unroll
    for (int j = 0; j < TPW; ++j) acc[r][j] = f32x4{0.f, 0.f, 0.f, 0.f};
  const short8v* Bp = reinterpret_cast<const short8v*>(Wp);
  for (int kb = 0; kb < KB; ++kb) {
    short8v a[RT];
#pragma unroll
    for (int r = 0; r < RT; ++r)
      a[r] = reinterpret_cast<const short8v*>(As)[(r * KB + kb) * 64 + lane];
#pragma unroll
    for (int j = 0; j < TPW; ++j) {
      int tile = w * TPW + j;
      short8v b = Bp[(tile * KB + kb) * 64 + lane];
#pragma unroll
      for (int r = 0; r < RT; ++r)
        acc[r][j] = __builtin_amdgcn_mfma_f32_16x16x32_bf16(a[r], b, acc[r][j], 0, 0, 0);
    }
  }
#pragma unroll
  for (int j = 0; j < TPW; ++j) {
    int col = (w * TPW + j) * 16 + (lane & 15);
    float bs = bias[col];
#pragma unroll
    for (int rt = 0; rt < RT; ++rt)
#pragma unroll
      for (int r = 0; r < 4; ++r) {
        int row = row0 + rt * 16 + (lane >> 4) * 4 + r;
        float v = acc[rt][j][r] + bs;
        if (ACT == 1) v = fmaxf(v, 0.f);
        if (OF32) Cf[(size_t)row * N + col] = v;
        if (OB16) Cb[(size_t)row * N + col] = f2bf(v);
      }
  }
}

// ---------------- LayerNorm (x -> bf16) ----------------
template<int C, int ACT, bool OUT16>
__global__ void k_ln(const float* in, void* out, const float* g, const float* b) {
  constexpr int T = (C < 256) ? C : 256;
  constexpr int EPT = C / T;
  int row = blockIdx.x, t = threadIdx.x;
  const float* ip = in + (size_t)row * C;
  float v[EPT];
  float s = 0.f, s2 = 0.f;
#pragma unroll
  for (int e = 0; e < EPT; ++e) { float xv = ip[t + e * T]; v[e] = xv; s += xv; s2 += xv * xv; }
#pragma unroll
  for (int m = 1; m <= 32; m <<= 1) { s += __shfl_xor(s, m); s2 += __shfl_xor(s2, m); }
  __shared__ float w1s[2], w2s[2];
  if (T > 64) {
    if ((t & 63) == 0) { w1s[t >> 6] = s; w2s[t >> 6] = s2; }
    __syncthreads();
    s = w1s[0] + w1s[1];
    s2 = w2s[0] + w2s[1];
  }
  float mu = s * (1.0f / C);
  float var = s2 * (1.0f / C) - mu * mu;
  float rs = rsqrtf(var + 1e-5f);
#pragma unroll
  for (int e = 0; e < EPT; ++e) {
    int c = t + e * T;
    float y = (v[e] - mu) * rs * g[c] + b[c];
    if (ACT == 1) y = fmaxf(y, 0.f);
    if (ACT == 2) y = elu(y);
    if (OUT16) ((unsigned short*)out)[(size_t)row * C + c] = f2bf(y);
    else       ((float*)out)[(size_t)row * C + c] = y;
  }
}

// ---------------- Fused GATv2 layer 1 (4-edge batched online softmax) ----------------
__global__ __launch_bounds__(256) void k_gat1(const int* __restrict__ offs,
                                              const int* __restrict__ src_s,
                                              const unsigned* __restrict__ xlh,  // [M][256] pairs
                                              const unsigned* __restrict__ xrh,
                                              const float* __restrict__ att,     // [512]
                                              const float* __restrict__ bg,
                                              const float* __restrict__ lg,
                                              const float* __restrict__ lb,
                                              unsigned* __restrict__ outh) {
  int n = blockIdx.x;
  int st = offs[n], en = offs[n + 1];
  int t = threadIdx.x;
  unsigned ur = xrh[(size_t)n * 256 + t];
  float xr0 = plo(ur), xr1 = phi(ur);
  float at0 = att[2 * t], at1 = att[2 * t + 1];
  float m = -3.0e38f, s = 0.f, acc0 = 0.f, acc1 = 0.f;
  int i = st;
  for (; i + 4 <= en; i += 4) {
    unsigned uu[4];
    float p[4];
#pragma unroll
    for (int q = 0; q < 4; ++q)
      uu[q] = xlh[(size_t)src_s[i + q] * 256 + t];
#pragma unroll
    for (int q = 0; q < 4; ++q)
      p[q] = at0 * lrelu(plo(uu[q]) + xr0) + at1 * lrelu(phi(uu[q]) + xr1);
#pragma unroll
    for (int mm = 1; mm <= 32; mm <<= 1) {
#pragma unroll
      for (int q = 0; q < 4; ++q) p[q] += __shfl_xor(p[q], mm);
    }
    float mn = fmaxf(m, fmaxf(fmaxf(p[0], p[1]), fmaxf(p[2], p[3])));
    float al = __expf(m - mn);
    float w[4];
#pragma unroll
    for (int q = 0; q < 4; ++q) w[q] = __expf(p[q] - mn);
    s = s * al + ((w[0] + w[1]) + (w[2] + w[3]));
    float a0 = 0.f, a1 = 0.f;
#pragma unroll
    for (int q = 0; q < 4; ++q) {
      a0 = fmaf(w[q], plo(uu[q]), a0);
      a1 = fmaf(w[q], phi(uu[q]), a1);
    }
    acc0 = acc0 * al + a0;
    acc1 = acc1 * al + a1;
    m = mn;
  }
  for (; i < en; ++i) {
    unsigned u = xlh[(size_t)src_s[i] * 256 + t];
    float x0 = plo(u), x1 = phi(u);
    float p = at0 * lrelu(x0 + xr0) + at1 * lrelu(x1 + xr1);
#pragma unroll
    for (int mm = 1; mm <= 32; mm <<= 1) p += __shfl_xor(p, mm);
    float mn = fmaxf(m, p);
    float al = __expf(m - mn);
    float we = __expf(p - mn);
    s = s * al + we;
    acc0 = acc0 * al + we * x0;
    acc1 = acc1 * al + we * x1;
    m = mn;
  }
  float inv = 1.0f / (s + 1e-16f);
  float v0 = acc0 * inv + bg[2 * t];
  float v1 = acc1 * inv + bg[2 * t + 1];
  float rs = v0 + v1, rs2 = v0 * v0 + v1 * v1;
#pragma unroll
  for (int mm = 1; mm <= 32; mm <<= 1) { rs += __shfl_xor(rs, mm); rs2 += __shfl_xor(rs2, mm); }
  __shared__ float r1[4], r2[4];
  if ((t & 63) == 0) { r1[t >> 6] = rs; r2[t >> 6] = rs2; }
  __syncthreads();
  rs = r1[0] + r1[1] + r1[2] + r1[3];
  rs2 = r2[0] + r2[1] + r2[2] + r2[3];
  float mu = rs * (1.0f / 512.0f);
  float var = rs2 * (1.0f / 512.0f) - mu * mu;
  float rsd = rsqrtf(var + 1e-5f);
  float y0 = elu((v0 - mu) * rsd * lg[2 * t] + lb[2 * t]);
  float y1 = elu((v1 - mu) * rsd * lg[2 * t + 1] + lb[2 * t + 1]);
  outh[(size_t)n * 256 + t] = packbf(y0, y1);
}

// ---------------- Fused GATv2 layer 2 (wave per node, 4-edge batched) ----------------
__global__ __launch_bounds__(256) void k_gat2(const int* __restrict__ offs,
                                              const int* __restrict__ src_s,
                                              const unsigned* __restrict__ xlh,  // [M][64] pairs
                                              const unsigned* __restrict__ xrh,
                                              const float* __restrict__ att,     // [128]
                                              const float* __restrict__ bg,
                                              const float* __restrict__ lg,
                                              const float* __restrict__ lb,
                                              float* __restrict__ emb,
                                              unsigned short* __restrict__ embh,
                                              int M) {
  int w = threadIdx.x >> 6, lane = threadIdx.x & 63;
  int n = blockIdx.x * 4 + w;
  if (n >= M) return;
  int st = offs[n], en = offs[n + 1];
  unsigned ur = xrh[(size_t)n * 64 + lane];
  float xr0 = plo(ur), xr1 = phi(ur);
  float at0 = att[2 * lane], at1 = att[2 * lane + 1];
  float m = -3.0e38f, s = 0.f, acc0 = 0.f, acc1 = 0.f;
  int i = st;
  for (; i + 4 <= en; i += 4) {
    unsigned uu[4];
    float p[4];
#pragma unroll
    for (int q = 0; q < 4; ++q)
      uu[q] = xlh[(size_t)src_s[i + q] * 64 + lane];
#pragma unroll
    for (int q = 0; q < 4; ++q)
      p[q] = at0 * lrelu(plo(uu[q]) + xr0) + at1 * lrelu(phi(uu[q]) + xr1);
#pragma unroll
    for (int mm = 1; mm <= 32; mm <<= 1) {
#pragma unroll
      for (int q = 0; q < 4; ++q) p[q] += __shfl_xor(p[q], mm);
    }
    float mn = fmaxf(m, fmaxf(fmaxf(p[0], p[1]), fmaxf(p[2], p[3])));
    float al = __expf(m - mn);
    float wq[4];
#pragma unroll
    for (int q = 0; q < 4; ++q) wq[q] = __expf(p[q] - mn);
    s = s * al + ((wq[0] + wq[1]) + (wq[2] + wq[3]));
    float a0 = 0.f, a1 = 0.f;
#pragma unroll
    for (int q = 0; q < 4; ++q) {
      a0 = fmaf(wq[q], plo(uu[q]), a0);
      a1 = fmaf(wq[q], phi(uu[q]), a1);
    }
    acc0 = acc0 * al + a0;
    acc1 = acc1 * al + a1;
    m = mn;
  }
  for (; i < en; ++i) {
    unsigned u = xlh[(size_t)src_s[i] * 64 + lane];
    float x0 = plo(u), x1 = phi(u);
    float p = at0 * lrelu(x0 + xr0) + at1 * lrelu(x1 + xr1);
#pragma unroll
    for (int mm = 1; mm <= 32; mm <<= 1) p += __shfl_xor(p, mm);
    float mn = fmaxf(m, p);
    float al = __expf(m - mn);
    float we = __expf(p - mn);
    s = s * al + we;
    acc0 = acc0 * al + we * x0;
    acc1 = acc1 * al + we * x1;
    m = mn;
  }
  float inv = 1.0f / (s + 1e-16f);
  float v0 = acc0 * inv + bg[2 * lane];
  float v1 = acc1 * inv + bg[2 * lane + 1];
  float rs = v0 + v1, rs2 = v0 * v0 + v1 * v1;
#pragma unroll
  for (int mm = 1; mm <= 32; mm <<= 1) { rs += __shfl_xor(rs, mm); rs2 += __shfl_xor(rs2, mm); }
  float mu = rs * (1.0f / 128.0f);
  float var = rs2 * (1.0f / 128.0f) - mu * mu;
  float rsd = rsqrtf(var + 1e-5f);
  float y0 = elu((v0 - mu) * rsd * lg[2 * lane] + lb[2 * lane]);
  float y1 = elu((v1 - mu) * rsd * lg[2 * lane + 1] + lb[2 * lane + 1]);
  *reinterpret_cast<float2*>(emb + (size_t)n * 128 + 2 * lane) = float2{y0, y1};
  reinterpret_cast<unsigned*>(embh)[(size_t)n * 64 + lane] = packbf(y0, y1);
}

// ---------------- Fused branch GEMM (N=384) + per-segment LN + relu ----------------
__global__ __launch_bounds__(256) void k_branch(const unsigned short* __restrict__ A,
    const unsigned short* __restrict__ Wp,
    const float* __restrict__ b0, const float* __restrict__ b1s, const float* __restrict__ b2s,
    const float* __restrict__ g0, const float* __restrict__ gb0,
    const float* __restrict__ g1, const float* __restrict__ gb1,
    const float* __restrict__ g2, const float* __restrict__ gb2,
    float* __restrict__ ff) {
  constexpr int KB = 4, TPW = 6;
  __shared__ short As[KB * 64 * 8];
  __shared__ float Cs[16 * 384];
  int row0 = blockIdx.x * 16;
  int t = threadIdx.x, lane = t & 63, w = t >> 6;
  for (int idx = t; idx < KB * 64; idx += 256) {
    int kb = idx >> 6, l = idx & 63;
    const short8v* sp = reinterpret_cast<const short8v*>(
        A + (size_t)(row0 + (l & 15)) * 128 + kb * 32 + (l >> 4) * 8);
    reinterpret_cast<short8v*>(As)[idx] = *sp;
  }
  __syncthreads();
  f32x4 acc[TPW];
#pragma unroll
  for (int j = 0; j < TPW; ++j) acc[j] = f32x4{0.f, 0.f, 0.f, 0.f};
  const short8v* Bp = reinterpret_cast<const short8v*>(Wp);
  for (int kb = 0; kb < KB; ++kb) {
    short8v a = reinterpret_cast<const short8v*>(As)[kb * 64 + lane];
#pragma unroll
    for (int j = 0; j < TPW; ++j) {
      int tile = w * TPW + j;
      short8v b = Bp[(tile * KB + kb) * 64 + lane];
      acc[j] = __builtin_amdgcn_mfma_f32_16x16x32_bf16(a, b, acc[j], 0, 0, 0);
    }
  }
#pragma unroll
  for (int j = 0; j < TPW; ++j) {
    int col = (w * TPW + j) * 16 + (lane & 15);
    int seg = col >> 7, cl = col & 127;
    const float* bp = (seg == 0) ? b0 : (seg == 1) ? b1s : b2s;
    float bs = bp[cl];
#pragma unroll
    for (int r = 0; r < 4; ++r)
      Cs[((lane >> 4) * 4 + r) * 384 + col] = acc[j][r] + bs;
  }
  __syncthreads();
  int row = t >> 4, l16 = t & 15;
#pragma unroll
  for (int seg = 0; seg < 3; ++seg) {
    float v[8];
    float s = 0.f, s2 = 0.f;
    int base = row * 384 + seg * 128 + l16 * 8;
#pragma unroll
    for (int k = 0; k < 8; ++k) { v[k] = Cs[base + k]; s += v[k]; s2 += v[k] * v[k]; }
#pragma unroll
    for (int mm = 1; mm <= 8; mm <<= 1) { s += __shfl_xor(s, mm); s2 += __shfl_xor(s2, mm); }
    float mu = s * (1.0f / 128.0f);
    float var = s2 * (1.0f / 128.0f) - mu * mu;
    float rsd = rsqrtf(var + 1e-5f);
    const float* gp = (seg == 0) ? g0 : (seg == 1) ? g1 : g2;
    const float* bp = (seg == 0) ? gb0 : (seg == 1) ? gb1 : gb2;
    float* op = ff + (size_t)(row0 + row) * 384 + seg * 128 + l16 * 8;
#pragma unroll
    for (int k = 0; k < 8; ++k) {
      int c = l16 * 8 + k;
      op[k] = fmaxf((v[k] - mu) * rsd * gp[c] + bp[c], 0.f);
    }
  }
}

// ---------------- Fused MLP heads (wave per row) ----------------
__global__ __launch_bounds__(256) void k_head_ret(const float* __restrict__ in, int ldi,
    const float* __restrict__ W1, const float* __restrict__ b1,
    const float* __restrict__ W2, const float* __restrict__ b2,
    const float* __restrict__ W3, const float* __restrict__ b3,
    float* __restrict__ out) {
  __shared__ float sh[4][224];
  int wid = threadIdx.x >> 6, lane = threadIdx.x & 63;
  int row = blockIdx.x * 4 + wid;
  const float2* rp = reinterpret_cast<const float2*>(in + (size_t)row * ldi);
  float2 f2 = rp[lane];
  sh[wid][2 * lane] = f2.x;
  sh[wid][2 * lane + 1] = f2.y;
  __syncthreads();
  float a = b1[lane];
#pragma unroll 8
  for (int k = 0; k < 128; ++k) a = fmaf(sh[wid][k], W1[k * 64 + lane], a);
  sh[wid][128 + lane] = fmaxf(a, 0.f);
  __syncthreads();
  if (lane < 32) {
    float a2 = b2[lane];
#pragma unroll 8
    for (int k = 0; k < 64; ++k) a2 = fmaf(sh[wid][128 + k], W2[k * 32 + lane], a2);
    sh[wid][192 + lane] = fmaxf(a2, 0.f);
  }
  __syncthreads();
  if (lane == 0) {
    float a3 = b3[0];
#pragma unroll
    for (int k = 0; k < 32; ++k) a3 = fmaf(sh[wid][192 + k], W3[k], a3);
    out[row] = tanhf(a3) * 0.1f;
  }
}

__global__ __launch_bounds__(256) void k_head_mov(const float* __restrict__ in, int ldi,
    const float* __restrict__ W1, const float* __restrict__ b1,
    const float* __restrict__ W2, const float* __restrict__ b2,
    float* __restrict__ out) {
  __shared__ float sh[4][192];
  int wid = threadIdx.x >> 6, lane = threadIdx.x & 63;
  int row = blockIdx.x * 4 + wid;
  const float2* rp = reinterpret_cast<const float2*>(in + (size_t)row * ldi);
  float2 f2 = rp[lane];
  sh[wid][2 * lane] = f2.x;
  sh[wid][2 * lane + 1] = f2.y;
  __syncthreads();
  float a = b1[lane];
#pragma unroll 8
  for (int k = 0; k < 128; ++k) a = fmaf(sh[wid][k], W1[k * 64 + lane], a);
  sh[wid][128 + lane] = fmaxf(a, 0.f);
  __syncthreads();
  if (lane < 2) {
    float a2 = b2[lane];
#pragma unroll 8
    for (int k = 0; k < 64; ++k) a2 = fmaf(sh[wid][128 + k], W2[k * 2 + lane], a2);
    out[(size_t)row * 2 + lane] = a2;
  }
}

__global__ __launch_bounds__(256) void k_head_rank(const float* __restrict__ in, int ldi,
    const float* __restrict__ W1, const float* __restrict__ b1,
    const float* __restrict__ W2, const float* __restrict__ b2,
    float* __restrict__ out) {
  __shared__ float sh[4][192];
  int wid = threadIdx.x >> 6, lane = threadIdx.x & 63;
  int row = blockIdx.x * 4 + wid;
  const float2* rp = reinterpret_cast<const float2*>(in + (size_t)row * ldi);
  float2 f2 = rp[lane];
  sh[wid][2 * lane] = f2.x;
  sh[wid][2 * lane + 1] = f2.y;
  __syncthreads();
  float a = b1[lane];
#pragma unroll 8
  for (int k = 0; k < 128; ++k) a = fmaf(sh[wid][k], W1[k * 64 + lane], a);
  sh[wid][128 + lane] = fmaxf(a, 0.f);
  __syncthreads();
  if (lane == 0) {
    float a2 = b2[0];
#pragma unroll 8
    for (int k = 0; k < 64; ++k) a2 = fmaf(sh[wid][128 + k], W2[k], a2);
    out[row] = 1.0f / (1.0f + expf(-a2));
  }
}

// ---------------- launch ----------------
extern "C" void kernel_launch(void* const* d_in, const int* in_sizes, int n_in,
                              void* d_out, int out_size, void* d_ws, size_t ws_size,
                              hipStream_t stream) {
  const float* x     = (const float*)d_in[0];
  const int*   ei    = (const int*)  d_in[1];
  const float* fn_g  = (const float*)d_in[2];
  const float* fn_b  = (const float*)d_in[3];
  const float* W_in  = (const float*)d_in[4];
  const float* b_in  = (const float*)d_in[5];
  const float* Wl1   = (const float*)d_in[6];
  const float* bl1   = (const float*)d_in[7];
  const float* Wr1   = (const float*)d_in[8];
  const float* br1   = (const float*)d_in[9];
  const float* att1  = (const float*)d_in[10];
  const float* bg1   = (const float*)d_in[11];
  const float* Wl2   = (const float*)d_in[12];
  const float* bl2   = (const float*)d_in[13];
  const float* Wr2   = (const float*)d_in[14];
  const float* br2   = (const float*)d_in[15];
  const float* att2  = (const float*)d_in[16];
  const float* bg2   = (const float*)d_in[17];
  const float* ln1_g = (const float*)d_in[18];
  const float* ln1_b = (const float*)d_in[19];
  const float* ln2_g = (const float*)d_in[20];
  const float* ln2_b = (const float*)d_in[21];
  const float* Wrf   = (const float*)d_in[22];
  const float* brf   = (const float*)d_in[23];
  const float* rf_g  = (const float*)d_in[24];
  const float* rf_b  = (const float*)d_in[25];
  const float* Wcf   = (const float*)d_in[26];
  const float* bcf   = (const float*)d_in[27];
  const float* cf_g  = (const float*)d_in[28];
  const float* cf_b  = (const float*)d_in[29];
  const float* Wkf   = (const float*)d_in[30];
  const float* bkf   = (const float*)d_in[31];
  const float* kf_g  = (const float*)d_in[32];
  const float* kf_b  = (const float*)d_in[33];
  const float* Wr1h  = (const float*)d_in[34];
  const float* br1h  = (const float*)d_in[35];
  const float* Wr2h  = (const float*)d_in[36];
  const float* br2h  = (const float*)d_in[37];
  const float* Wr3h  = (const float*)d_in[38];
  const float* br3h  = (const float*)d_in[39];
  const float* Wc1h  = (const float*)d_in[40];
  const float* bc1h  = (const float*)d_in[41];
  const float* Wc2h  = (const float*)d_in[42];
  const float* bc2h  = (const float*)d_in[43];
  const float* Wk1h  = (const float*)d_in[44];
  const float* bk1h  = (const float*)d_in[45];
  const float* Wk2h  = (const float*)d_in[46];
  const float* bk2h  = (const float*)d_in[47];

  const int M  = in_sizes[0] / 128;   // 20000
  const int E0 = in_sizes[1] / 2;     // 320000
  const int ET = E0 + M;              // 340000

  char* base = (char*)d_ws;
  size_t off = 0;
  auto carve = [&](size_t bytes) -> char* {
    off = (off + 255) & ~(size_t)255;
    char* p = base + off;
    off += bytes;
    return p;
  };
  const size_t B512 = (size_t)M * 512 * 2;  // bf16
  const size_t B128 = (size_t)M * 128 * 2;
  unsigned short* hnh  = (unsigned short*)carve(B128);
  unsigned short* h0h  = (unsigned short*)carve(B128);
  unsigned short* xl1h = (unsigned short*)carve(B512);
  unsigned short* xr1h = (unsigned short*)carve(B512);
  unsigned short* g1h  = (unsigned short*)carve(B512);
  unsigned short* xl2h = (unsigned short*)carve(B128);
  unsigned short* xr2h = (unsigned short*)carve(B128);
  unsigned short* embh = (unsigned short*)carve(B128);
  int* src_s = (int*)carve((size_t)ET * sizeof(int));
  int* cnt   = (int*)carve((size_t)2 * M * sizeof(int));
  int* cur   = cnt + M;
  int* offs  = (int*)carve((size_t)(M + 1) * sizeof(int));
  unsigned short* Winp = (unsigned short*)carve(128 * 128 * 2);
  unsigned short* Wl1p = (unsigned short*)carve(128 * 512 * 2);
  unsigned short* Wr1p = (unsigned short*)carve(128 * 512 * 2);
  unsigned short* Wl2p = (unsigned short*)carve(512 * 128 * 2);
  unsigned short* Wr2p = (unsigned short*)carve(512 * 128 * 2);
  unsigned short* Wtp  = (unsigned short*)carve(3 * 128 * 128 * 2);
  // ff [M][384] f32 overlays xl1h/xr1h (dead after k_gat1)
  float* ff = (float*)xl1h;
  (void)ws_size; (void)n_in; (void)out_size;

  // CSR by dst
  hipMemsetAsync(cnt, 0, (size_t)2 * M * sizeof(int), stream);
  k_count<<<(ET + 255) / 256, 256, 0, stream>>>(ei, cnt, E0, ET);
  k_scan2<<<1, 1024, 0, stream>>>(cnt, offs, M);
  k_scatter<<<(ET + 255) / 256, 256, 0, stream>>>(ei, offs, cur, src_s, E0, ET);

  // weight packing (one launch)
  k_pack_all<<<256, 256, 0, stream>>>(W_in, Wl1, Wr1, Wl2, Wr2, Wrf, Wcf, Wkf,
                                      Winp, Wl1p, Wr1p, Wl2p, Wr2p,
                                      Wtp, Wtp + 16384, Wtp + 32768);

  // node pipeline (bf16 flow, f32 accum)
  k_ln<128, 0, true><<<M, 128, 0, stream>>>(x, hnh, fn_g, fn_b);
  k_mfma<128, 128, 2, 1, false, true><<<M / 32, 256, 0, stream>>>(hnh, Winp, b_in, nullptr, h0h);
  k_mfma<128, 512, 2, 0, false, true><<<M / 32, 256, 0, stream>>>(h0h, Wl1p, bl1, nullptr, xl1h);
  k_mfma<128, 512, 2, 0, false, true><<<M / 32, 256, 0, stream>>>(h0h, Wr1p, br1, nullptr, xr1h);
  k_gat1<<<M, 256, 0, stream>>>(offs, src_s, (const unsigned*)xl1h, (const unsigned*)xr1h,
                                att1, bg1, ln1_g, ln1_b, (unsigned*)g1h);
  k_mfma<512, 128, 2, 0, false, true><<<M / 32, 256, 0, stream>>>(g1h, Wl2p, bl2, nullptr, xl2h);
  k_mfma<512, 128, 2, 0, false, true><<<M / 32, 256, 0, stream>>>(g1h, Wr2p, br2, nullptr, xr2h);

  float* out_ret  = (float*)d_out;
  float* out_mov  = out_ret + M;
  float* out_rank = out_ret + 3 * M;
  float* emb      = out_ret + 4 * M;
  k_gat2<<<(M + 3) / 4, 256, 0, stream>>>(offs, src_s, (const unsigned*)xl2h,
                                          (const unsigned*)xr2h, att2, bg2,
                                          ln2_g, ln2_b, emb, embh, M);

  // fused feature branches (GEMM N=384 + LN + relu)
  k_branch<<<M / 16, 256, 0, stream>>>(embh, Wtp, brf, bcf, bkf,
                                       rf_g, rf_b, cf_g, cf_b, kf_g, kf_b, ff);

  // heads (read ff with stride 384, offsets 0/128/256)
  k_head_ret<<<M / 4, 256, 0, stream>>>(ff, 384, Wr1h, br1h, Wr2h, br2h, Wr3h, br3h, out_ret);
  k_head_mov<<<M / 4, 256, 0, stream>>>(ff + 128, 384, Wc1h, bc1h, Wc2h, bc2h, out_mov);
  k_head_rank<<<M / 4, 256, 0, stream>>>(ff + 256, 384, Wk1h, bk1h, Wk2h, bk2h, out_rank);
}